// Round 7
// baseline (1681.269 us; speedup 1.0000x reference)
//
#include <hip/hip_runtime.h>
#include <cstdint>
#include <cstddef>

#define DI __device__ __forceinline__

typedef __bf16 bf16x8 __attribute__((ext_vector_type(8)));
typedef float  f32x4  __attribute__((ext_vector_type(4)));

constexpr int kE = 1024;
constexpr int kM = 8192;
constexpr float kSlope = 0.01f;

DI float bf2f(ushort u) { union { uint32_t i; float f; } v; v.i = ((uint32_t)u) << 16; return v.f; }
DI ushort f2bf(float f) {
    union { float f; uint32_t i; } v; v.f = f;
    return (ushort)((v.i + 0x7FFFu + ((v.i >> 16) & 1u)) >> 16);
}
DI bf16x8 ld8f(const float* p) {
    const float4 f0 = *(const float4*)p;
    const float4 f1 = *(const float4*)(p + 4);
    union { bf16x8 v; ushort u[8]; } o;
    o.u[0] = f2bf(f0.x); o.u[1] = f2bf(f0.y); o.u[2] = f2bf(f0.z); o.u[3] = f2bf(f0.w);
    o.u[4] = f2bf(f1.x); o.u[5] = f2bf(f1.y); o.u[6] = f2bf(f1.z); o.u[7] = f2bf(f1.w);
    return o.v;
}
template<typename T> DI float ldf(const T* p);
template<> DI float ldf<ushort>(const ushort* p) { return bf2f(*p); }
template<> DI float ldf<float>(const float* p) { return *p; }

DI void gload16(const void* g, void* lds) {
    __builtin_amdgcn_global_load_lds((const __attribute__((address_space(1))) void*)g,
                                     (__attribute__((address_space(3))) void*)lds, 16, 0, 0);
}

// XOR swizzle helper (16B-slot granularity on bits 4..6)
DI int swz7(int r) { return ((r ^ (r >> 3)) & 7) << 4; }

// ---------------------------------------------------------------------------
// cvt_pack: fp32 weights -> packed bf16 WB; x,y -> bf16; biases -> packed fp32
// ---------------------------------------------------------------------------
struct PtrTab { const float* w[16]; const float* b[16]; const float* x; const float* y; };

__global__ __launch_bounds__(256)
void cvt_pack(PtrTab t, ushort* __restrict__ WB, ushort* __restrict__ Xb,
              ushort* __restrict__ Yb, float* __restrict__ BP)
{
    const int blk = blockIdx.x, tid = threadIdx.x;
    if (blk < 16384) {
        const float* src; ushort* dst; size_t idx;
        if (blk < 8192)       { const int w = blk >> 9; idx = (size_t)(blk & 511) * 2048 + tid * 8; src = t.w[w]; dst = WB + (size_t)w * 1048576; }
        else if (blk < 12288) { idx = (size_t)(blk - 8192) * 2048 + tid * 8;  src = t.x; dst = Xb; }
        else                  { idx = (size_t)(blk - 12288) * 2048 + tid * 8; src = t.y; dst = Yb; }
        *(bf16x8*)(dst + idx) = ld8f(src + idx);
    } else {
        const size_t i = (size_t)(blk - 16384) * 2048 + tid * 8;
        const int w = (int)(i >> 10), off = (int)(i & 1023);
        *(float4*)(BP + i)     = *(const float4*)(t.b[w] + off);
        *(float4*)(BP + i + 4) = *(const float4*)(t.b[w] + off + 4);
    }
}

// ---------------------------------------------------------------------------
// 128x128-tile bf16 GEMM (narrow N): out[8192,N] = epi(A @ W^T + bias)
// BK=32, 4 waves(2x2), global_load_lds staging, double-buffered.
// ---------------------------------------------------------------------------
template<int ACT, int RESID, typename TR, typename TO>
__global__ __launch_bounds__(256)
void gemm_bf16(const ushort* __restrict__ A, const ushort* __restrict__ W,
               const float* __restrict__ bias, const TR* __restrict__ resb,
               TO* __restrict__ out, int N)
{
    __shared__ __align__(16) char sm[2][16384];   // [buf][A 8K | W 8K]
    constexpr int K = 1024;
    const int tid = threadIdx.x, l = tid & 63, wid = tid >> 6;
    const int wm = wid >> 1, wn = wid & 1;

    const int cpx = gridDim.x >> 3;
    const int sb = (blockIdx.x & 7) * cpx + (blockIdx.x >> 3);
    const int nbn = N >> 7;
    const int bm = sb / nbn, bn = sb - bm * nbn;
    const size_t row0 = (size_t)bm << 7, col0 = (size_t)bn << 7;

    // staging source precompute: o = (wid*2+i)*1024 + l*16
    const int o0 = (wid * 2) * 1024 + (l << 4), o1 = o0 + 1024;
    const int r0s = o0 >> 6, c0s = ((o0 >> 4) & 3) ^ ((r0s >> 1) & 3);
    const int r1s = o1 >> 6, c1s = ((o1 >> 4) & 3) ^ ((r1s >> 1) & 3);
    const ushort* gA0 = A + (row0 + r0s) * K + c0s * 8;
    const ushort* gA1 = A + (row0 + r1s) * K + c1s * 8;
    const ushort* gW0 = W + (col0 + r0s) * K + c0s * 8;
    const ushort* gW1 = W + (col0 + r1s) * K + c1s * 8;
    const int d0 = (wid * 2) * 1024, d1 = d0 + 1024;

    f32x4 acc[4][4] = {};

    { // prologue: stage tile 0
        gload16(gA0, sm[0] + d0); gload16(gA1, sm[0] + d1);
        gload16(gW0, sm[0] + 8192 + d0); gload16(gW1, sm[0] + 8192 + d1);
    }
    __syncthreads();

    for (int kt = 0; kt < 32; ++kt) {
        const int cur = kt & 1;
        if (kt + 1 < 32) {
            const int ko = (kt + 1) << 5;
            char* nb = sm[cur ^ 1];
            gload16(gA0 + ko, nb + d0); gload16(gA1 + ko, nb + d1);
            gload16(gW0 + ko, nb + 8192 + d0); gload16(gW1 + ko, nb + 8192 + d1);
        }
        const char* At = sm[cur];
        const char* Wt = sm[cur] + 8192;
        bf16x8 af[4], bfr[4];
        #pragma unroll
        for (int mi = 0; mi < 4; ++mi) {
            const int r = (wm << 6) + (mi << 4) + (l & 15);
            af[mi] = *(const bf16x8*)(At + r * 64 + ((((l >> 4) ^ ((r >> 1) & 3))) << 4));
        }
        #pragma unroll
        for (int ni = 0; ni < 4; ++ni) {
            const int r = (wn << 6) + (ni << 4) + (l & 15);
            bfr[ni] = *(const bf16x8*)(Wt + r * 64 + ((((l >> 4) ^ ((r >> 1) & 3))) << 4));
        }
        #pragma unroll
        for (int mi = 0; mi < 4; ++mi)
            #pragma unroll
            for (int ni = 0; ni < 4; ++ni)
                acc[mi][ni] = __builtin_amdgcn_mfma_f32_16x16x32_bf16(af[mi], bfr[ni], acc[mi][ni], 0, 0, 0);
        __syncthreads();
    }

    // epilogue: C/D layout col=lane&15, row=(lane>>4)*4+reg
    const int cr = (l >> 4) << 2, cc = l & 15;
    #pragma unroll
    for (int mi = 0; mi < 4; ++mi) {
        #pragma unroll
        for (int ni = 0; ni < 4; ++ni) {
            const size_t gr = row0 + (wm << 6) + (mi << 4) + cr;
            const size_t gc = col0 + (wn << 6) + (ni << 4) + cc;
            const float bv = bias[gc];
            #pragma unroll
            for (int r = 0; r < 4; ++r) {
                float v = acc[mi][ni][r] + bv;
                if (ACT) v = v > 0.f ? v : v * kSlope;
                const size_t off = (gr + r) * (size_t)N + gc;
                if (RESID) v += ldf(resb + off);
                if constexpr (sizeof(TO) == 4) out[off] = v;
                else                           out[off] = f2bf(v);
            }
        }
    }
}

// ---------------------------------------------------------------------------
// 256x256-tile bf16 GEMM (wide N): BK=32, 8 waves (2M x 4N), per-wave 128x64,
// double-buffered 64 KB LDS, global_load_lds staging.
// __launch_bounds__(512, 1): 1 block/CU min -> 256-VGPR budget; the (512,2)
// variant capped at 128 VGPRs and spilled acc to scratch (round-6 post-mortem:
// WRITE_SIZE 1.1 GB/dispatch, MfmaUtil 4.4%).
// VT mode (col0 >= vtcol0): swapped-operand MFMA -> C^T, transposed store to
// vt_out[(b*1024 + d)*1024 + t] for attention's pre-transposed V.
// ---------------------------------------------------------------------------
template<int VT>
__global__ __launch_bounds__(512, 1)
void gemm256(const ushort* __restrict__ A, const ushort* __restrict__ W,
             const float* __restrict__ bias, ushort* __restrict__ out, int N,
             ushort* __restrict__ vt_out, int vtcol0)
{
    __shared__ __align__(16) char sm[2][32768];   // [buf][A 16K | W 16K]
    constexpr int K = 1024;
    const int tid = threadIdx.x, l = tid & 63, wid = tid >> 6;
    const int wm = wid >> 2, wn = wid & 3;

    const int cpx = gridDim.x >> 3;
    const int sb = (blockIdx.x & 7) * cpx + (blockIdx.x >> 3);
    const int nbn = N >> 8;
    const int bm = sb / nbn, bn = sb - bm * nbn;
    const size_t row0 = (size_t)bm << 8, col0 = (size_t)bn << 8;
    const bool isvt = VT && ((int)col0 >= vtcol0);

    // staging: slot s = tid covers rows 0..127, slot tid+512 rows 128..255.
    // row r = s>>2 (64B rows), chunk c = (s&3) ^ ((r>>1)&3).
    const int r0s = tid >> 2, c0s = (tid & 3) ^ ((r0s >> 1) & 3);
    const ushort* gA0 = A + (row0 + r0s) * K + c0s * 8;
    const ushort* gA1 = gA0 + (size_t)128 * K;     // (r0s+128): same chunk xor
    const ushort* gW0 = W + (col0 + r0s) * K + c0s * 8;
    const ushort* gW1 = gW0 + (size_t)128 * K;
    const int d0 = wid * 1024;                     // wave-uniform LDS base

    f32x4 acc[8][4] = {};

    gload16(gA0, sm[0] + d0);          gload16(gA1, sm[0] + 8192 + d0);
    gload16(gW0, sm[0] + 16384 + d0);  gload16(gW1, sm[0] + 24576 + d0);
    __syncthreads();

    for (int kt = 0; kt < 32; ++kt) {
        const int cur = kt & 1;
        if (kt + 1 < 32) {
            const int ko = (kt + 1) << 5;
            char* nb = sm[cur ^ 1];
            gload16(gA0 + ko, nb + d0);          gload16(gA1 + ko, nb + 8192 + d0);
            gload16(gW0 + ko, nb + 16384 + d0);  gload16(gW1 + ko, nb + 24576 + d0);
        }
        const char* At = sm[cur];
        const char* Wt = sm[cur] + 16384;
        bf16x8 af[8], bfr[4];
        #pragma unroll
        for (int mi = 0; mi < 8; ++mi) {
            const int r = (wm << 7) + (mi << 4) + (l & 15);
            af[mi] = *(const bf16x8*)(At + r * 64 + (((l >> 4) ^ ((r >> 1) & 3)) << 4));
        }
        #pragma unroll
        for (int ni = 0; ni < 4; ++ni) {
            const int r = (wn << 6) + (ni << 4) + (l & 15);
            bfr[ni] = *(const bf16x8*)(Wt + r * 64 + (((l >> 4) ^ ((r >> 1) & 3)) << 4));
        }
        if (!isvt) {
            #pragma unroll
            for (int mi = 0; mi < 8; ++mi)
                #pragma unroll
                for (int ni = 0; ni < 4; ++ni)
                    acc[mi][ni] = __builtin_amdgcn_mfma_f32_16x16x32_bf16(af[mi], bfr[ni], acc[mi][ni], 0, 0, 0);
        } else {
            #pragma unroll
            for (int mi = 0; mi < 8; ++mi)
                #pragma unroll
                for (int ni = 0; ni < 4; ++ni)
                    acc[mi][ni] = __builtin_amdgcn_mfma_f32_16x16x32_bf16(bfr[ni], af[mi], acc[mi][ni], 0, 0, 0);
        }
        __syncthreads();
    }

    const int cr = (l >> 4) << 2, cc = l & 15;
    if (!isvt) {
        #pragma unroll
        for (int mi = 0; mi < 8; ++mi) {
            #pragma unroll
            for (int ni = 0; ni < 4; ++ni) {
                const size_t gr = row0 + (wm << 7) + (mi << 4) + cr;
                const size_t gc = col0 + (wn << 6) + (ni << 4) + cc;
                const float bv = bias[gc];
                #pragma unroll
                for (int r = 0; r < 4; ++r) {
                    const float v = acc[mi][ni][r] + bv;
                    out[(gr + r) * (size_t)N + gc] = f2bf(v);
                }
            }
        }
    } else if (VT) {
        #pragma unroll
        for (int mi = 0; mi < 8; ++mi) {
            const size_t t_glob = row0 + (wm << 7) + (mi << 4) + cc;
            const size_t bb = t_glob >> 10;
            const int tt = (int)(t_glob & 1023);
            #pragma unroll
            for (int ni = 0; ni < 4; ++ni) {
                const int gcb = (int)col0 + (wn << 6) + (ni << 4) + cr;
                const int dbase = gcb - vtcol0;
                #pragma unroll
                for (int r = 0; r < 4; ++r) {
                    const float v = acc[mi][ni][r] + bias[gcb + r];
                    vt_out[(((bb << 10) + dbase + r) << 10) + tt] = f2bf(v);
                }
            }
        }
    }
}

// ---------------------------------------------------------------------------
// Flash attention. One block = (b, h, 64 q-rows); 4 waves x 16 q-rows.
// Q/K/QV bf16 row stride ld; V comes PRE-TRANSPOSED: VT[(b*8+h)*128+d][1024 t].
// K staged row-major [64][128]bf16 (XOR-swz) via reg->LDS uint4 stores;
// V staged [128 d][64 t] via uint4 stores (XOR-swz), PV B-frags contiguous
// ds_read_b128. P re-laid-out via per-wave LDS. Output stride 1024.
// ---------------------------------------------------------------------------
template<int ADD_QV>
__global__ __launch_bounds__(256)
void attn_fwd(const ushort* __restrict__ Q, const ushort* __restrict__ K,
              const ushort* __restrict__ VT, const ushort* __restrict__ QV,
              ushort* __restrict__ O, int ld, float scale)
{
    __shared__ __align__(16) char Kt[64 * 256];    // 16 KiB
    __shared__ __align__(16) char Vt[128 * 128];   // 16 KiB: [d][64 t] bf16
    __shared__ __align__(16) char Pl[4][2048];     // per-wave 16x64 bf16

    const int tid = threadIdx.x;
    const int l = tid & 63, w = tid >> 6;

    const int cpx = gridDim.x >> 3;                 // 1024 blocks -> 128
    const int sb = (blockIdx.x & 7) * cpx + (blockIdx.x >> 3);
    const int qt = sb & 15;
    const int bh = sb >> 4;
    const int h = bh & 7, b = bh >> 3;

    const size_t bi = ((size_t)b << 10) * (size_t)ld + ((size_t)h << 7);
    const size_t bo = ((size_t)b << 10) * 1024 + ((size_t)h << 7);
    const size_t vtoff = ((size_t)bh) << 17;        // (b*8+h)*128*1024
    const size_t qrow0 = (size_t)(qt << 6) + (w << 4);

    // Q fragments (A-side: lane&15 = q-row, (lane>>4)*8 = k-offset)
    bf16x8 qf[4];
    #pragma unroll
    for (int kk = 0; kk < 4; ++kk)
        qf[kk] = *(const bf16x8*)(Q + bi + (qrow0 + (l & 15)) * ld + (kk << 5) + ((l >> 4) << 3));

    f32x4 oacc[8] = {};
    float mrow[4] = {-1e30f, -1e30f, -1e30f, -1e30f};
    float lrow[4] = {0.f, 0.f, 0.f, 0.f};

    const int sr = tid >> 4, sc = tid & 15;   // K staging: row group / 16B chunk

    // V staging precompute (kt0-independent): LDS slot S=it*256+tid -> (d=S>>3, s=S&7)
    int vofs[4];
    #pragma unroll
    for (int it = 0; it < 4; ++it) {
        const int d = it * 32 + (tid >> 3);
        const int s = tid & 7;
        const int c = s ^ ((d ^ (d >> 3)) & 7);
        vofs[it] = d * 1024 + c * 8;
    }
    const int vdst = tid * 16;

    for (int kt0 = 0; kt0 < 16; ++kt0) {
        __syncthreads();                      // previous tile's LDS reads done
        #pragma unroll
        for (int it = 0; it < 4; ++it) {
            const int r = sr + (it << 4);     // key row 0..63
            uint4 kv = *(const uint4*)(K + bi + (size_t)(kt0 * 64 + r) * ld + (sc << 3));
            *(uint4*)(Kt + r * 256 + ((sc << 4) ^ swz7(r))) = kv;
        }
        #pragma unroll
        for (int it = 0; it < 4; ++it) {
            uint4 vv = *(const uint4*)(VT + vtoff + (size_t)(kt0 << 6) + vofs[it]);
            *(uint4*)(Vt + it * 4096 + vdst) = vv;
        }
        __syncthreads();

        // S = Q K^T  (lane holds S[q=(l>>4)*4+r][t=(l&15)+16*ni])
        f32x4 sacc[4] = {};
        #pragma unroll
        for (int ni = 0; ni < 4; ++ni) {
            const int r = (l & 15) + (ni << 4);
            #pragma unroll
            for (int kk = 0; kk < 4; ++kk) {
                bf16x8 kf = *(const bf16x8*)(Kt + r * 256 + ((((kk << 2) + (l >> 4)) << 4) ^ swz7(r)));
                sacc[ni] = __builtin_amdgcn_mfma_f32_16x16x32_bf16(qf[kk], kf, sacc[ni], 0, 0, 0);
            }
        }
        #pragma unroll
        for (int ni = 0; ni < 4; ++ni) sacc[ni] *= scale;

        // online softmax (rows reduced across the 16-lane subgroup)
        float corr[4];
        #pragma unroll
        for (int r = 0; r < 4; ++r) {
            float m0 = fmaxf(fmaxf(sacc[0][r], sacc[1][r]), fmaxf(sacc[2][r], sacc[3][r]));
            #pragma unroll
            for (int m = 1; m < 16; m <<= 1) m0 = fmaxf(m0, __shfl_xor(m0, m, 64));
            const float mn = fmaxf(mrow[r], m0);
            corr[r] = __expf(mrow[r] - mn);
            mrow[r] = mn;
        }
        float ps[4] = {0.f, 0.f, 0.f, 0.f};
        ushort pb[4][4];
        #pragma unroll
        for (int ni = 0; ni < 4; ++ni)
            #pragma unroll
            for (int r = 0; r < 4; ++r) {
                const float p = __expf(sacc[ni][r] - mrow[r]);
                ps[r] += p;
                pb[ni][r] = f2bf(p);
            }
        #pragma unroll
        for (int r = 0; r < 4; ++r) {
            float s = ps[r];
            #pragma unroll
            for (int m = 1; m < 16; m <<= 1) s += __shfl_xor(s, m, 64);
            lrow[r] = lrow[r] * corr[r] + s;
        }
        #pragma unroll
        for (int nd = 0; nd < 8; ++nd)
            #pragma unroll
            for (int r = 0; r < 4; ++r) oacc[nd][r] *= corr[r];

        // P -> per-wave LDS (re-layout to A-fragment), then PV
        char* pw = Pl[w];
        #pragma unroll
        for (int ni = 0; ni < 4; ++ni)
            #pragma unroll
            for (int r = 0; r < 4; ++r) {
                const int q = ((l >> 4) << 2) + r;
                const int t = (l & 15) + (ni << 4);
                *(ushort*)(pw + q * 128 + ((t * 2) ^ swz7(q))) = pb[ni][r];
            }
        #pragma unroll
        for (int tg = 0; tg < 2; ++tg) {
            const int q = l & 15;
            bf16x8 pf = *(const bf16x8*)(pw + q * 128 + ((((tg << 2) + (l >> 4)) << 4) ^ swz7(q)));
            #pragma unroll
            for (int nd = 0; nd < 8; ++nd) {
                const int d = (nd << 4) + (l & 15);
                const int m = (d ^ (d >> 3)) & 7;
                bf16x8 vf = *(const bf16x8*)(Vt + d * 128 + ((((tg << 2) + (l >> 4)) ^ m) << 4));
                oacc[nd] = __builtin_amdgcn_mfma_f32_16x16x32_bf16(pf, vf, oacc[nd], 0, 0, 0);
            }
        }
    }

    // epilogue: O /= l  (+ qv), bf16 store
    const size_t orow = qrow0 + ((l >> 4) << 2);
    #pragma unroll
    for (int r = 0; r < 4; ++r) {
        const float inv = 1.f / lrow[r];
        #pragma unroll
        for (int nd = 0; nd < 8; ++nd) {
            const size_t c = (l & 15) + (nd << 4);
            float v = oacc[nd][r] * inv;
            if (ADD_QV) v += bf2f(QV[bi + (orow + r) * ld + c]);
            O[bo + (orow + r) * 1024 + c] = f2bf(v);
        }
    }
}

// ---------------------------------------------------------------------------
// LayerNorm over (S,E) per batch on bf16 h1.
// ---------------------------------------------------------------------------
__global__ void ln_partial(const ushort* __restrict__ h1, float2* __restrict__ part)
{
    __shared__ float sa[8];
    const size_t off = ((size_t)blockIdx.x) << 15;
    float s = 0.f, s2 = 0.f;
    for (int i = threadIdx.x; i < 4096; i += 256) {
        uint4 u = *(const uint4*)(h1 + off + (size_t)i * 8);
        const ushort* e = (const ushort*)&u;
        #pragma unroll
        for (int j = 0; j < 8; ++j) { const float v = bf2f(e[j]); s += v; s2 += v * v; }
    }
    #pragma unroll
    for (int m = 1; m < 64; m <<= 1) { s += __shfl_xor(s, m, 64); s2 += __shfl_xor(s2, m, 64); }
    const int w = threadIdx.x >> 6;
    if ((threadIdx.x & 63) == 0) { sa[w * 2] = s; sa[w * 2 + 1] = s2; }
    __syncthreads();
    if (threadIdx.x == 0)
        part[blockIdx.x] = make_float2(sa[0] + sa[2] + sa[4] + sa[6], sa[1] + sa[3] + sa[5] + sa[7]);
}

__global__ void ln_finish(const float2* __restrict__ part, float2* __restrict__ stats)
{
    const int b = threadIdx.x;
    if (b < 8) {
        float s = 0.f, s2 = 0.f;
        for (int c = 0; c < 32; ++c) { const float2 v = part[b * 32 + c]; s += v.x; s2 += v.y; }
        const float mu = s * (1.f / 1048576.f);
        const float var = s2 * (1.f / 1048576.f) - mu * mu;
        stats[b] = make_float2(mu, rsqrtf(var + 1e-5f));
    }
}

__global__ void ln_apply(const ushort* __restrict__ h1, const float2* __restrict__ stats,
                         const float* __restrict__ gw, const float* __restrict__ gb,
                         ushort* __restrict__ hn)
{
    const size_t i = ((size_t)blockIdx.x * 256 + threadIdx.x) * 8;
    const int b = (int)(i >> 20);
    const size_t r = i & 1048575;
    const float2 st = stats[b];
    uint4 uv = *(const uint4*)(h1 + i);
    const float4 w0 = *(const float4*)(gw + r);
    const float4 w1 = *(const float4*)(gw + r + 4);
    const float4 b0 = *(const float4*)(gb + r);
    const float4 b1 = *(const float4*)(gb + r + 4);
    const float wv[8] = {w0.x, w0.y, w0.z, w0.w, w1.x, w1.y, w1.z, w1.w};
    const float bv[8] = {b0.x, b0.y, b0.z, b0.w, b1.x, b1.y, b1.z, b1.w};
    const ushort* ev = (const ushort*)&uv;
    ushort o[8];
    #pragma unroll
    for (int j = 0; j < 8; ++j)
        o[j] = f2bf((bf2f(ev[j]) - st.x) * st.y * wv[j] + bv[j]);
    *(uint4*)(hn + i) = *(const uint4*)o;
}

// ---------------------------------------------------------------------------
extern "C" void kernel_launch(void* const* d_in, const int* in_sizes, int n_in,
                              void* d_out, int out_size, void* d_ws, size_t ws_size,
                              hipStream_t stream)
{
    (void)in_sizes; (void)n_in; (void)out_size; (void)ws_size;
    auto P = [&](int i) { return (const float*)d_in[i]; };

    const size_t MB = 1u << 20;
    char* ws = (char*)d_ws;
    ushort* WB = (ushort*)ws;                       // 32 MB packed bf16 weights
    ushort* R0 = (ushort*)(ws + 32 * MB);           // 32 MB (48 MB during SA)
    ushort* R1 = (ushort*)(ws + 64 * MB);           // 32 MB
    ushort* A0 = (ushort*)(ws + 96 * MB);           // 16 MB
    ushort* A1 = (ushort*)(ws + 112 * MB);          // 16 MB
    float*  BP = (float*)(ws + 128 * MB);           // 64 KB packed fp32 biases
    float2* PART = (float2*)(ws + 128 * MB + 65536);
    float2* STATS = PART + 256;

    PtrTab tab;
    const int wsrc[16] = {2,4,6,8,10,14,16,18,20,22,24,26,28,30,32,34};
    for (int i = 0; i < 16; ++i) { tab.w[i] = P(wsrc[i]); tab.b[i] = P(wsrc[i] + 1); }
    tab.x = P(0); tab.y = P(1);

    const dim3 blk(256), blk5(512);
    const float SA_SCALE = 0.08838834764831845f;    // 1/sqrt(128)
    auto Wp = [&](int w) { return WB + (size_t)w * 1048576; };
    auto Bp = [&](int w) { return BP + (size_t)w * 1024; };

    cvt_pack<<<dim3(16392), blk, 0, stream>>>(tab, WB, A0, A1, BP);

    // --- cross attention ---
    // q|qv -> R0 (stride 2048)
    gemm256<0><<<dim3(256), blk5, 0, stream>>>(A0, Wp(0), Bp(0), R0, 2048, nullptr, 0);
    // k -> R1 (stride 2048, cols 0..1023); kv^T -> A0 (VT layout)
    gemm256<1><<<dim3(256), blk5, 0, stream>>>(A1, Wp(2), Bp(2), R1, 2048, A0, 1024);
    attn_fwd<1><<<dim3(1024), blk, 0, stream>>>(R0, R1, A0, R0 + 1024, A1, 2048, 1.0f);            // -> A1
    // h1 = x + o(ca) -> A0
    gemm_bf16<0,1,float,ushort><<<dim3(512), blk, 0, stream>>>(A1, Wp(4), Bp(4), P(0), A0, 1024);

    // --- LayerNorm over (S,E) per batch: h1=A0 -> hn=A1 ---
    ln_partial<<<dim3(256), blk, 0, stream>>>(A0, PART);
    ln_finish<<<dim3(1), dim3(64), 0, stream>>>(PART, STATS);
    ln_apply<<<dim3(4096), blk, 0, stream>>>(A0, STATS, P(12), P(13), A1);

    // --- FeedForward: hn=A1 -> h2=A0 ---
    gemm_bf16<1,0,ushort,ushort><<<dim3(512), blk, 0, stream>>>(A1, Wp(5), Bp(5), (const ushort*)nullptr, R0, 1024);
    gemm_bf16<1,0,ushort,ushort><<<dim3(512), blk, 0, stream>>>(R0, Wp(6), Bp(6), (const ushort*)nullptr, R1, 1024);
    gemm_bf16<1,1,ushort,ushort><<<dim3(512), blk, 0, stream>>>(R1, Wp(7), Bp(7), A1, A0, 1024);

    // --- self attention 1 ---
    // q|k -> R0 (stride 3072, cols 0..2047); v^T -> A1 (VT layout)
    gemm256<1><<<dim3(384), blk5, 0, stream>>>(A0, Wp(8), Bp(8), R0, 3072, A1, 2048);
    attn_fwd<0><<<dim3(1024), blk, 0, stream>>>(R0, R0 + 1024, A1, nullptr, A0, 3072, SA_SCALE);   // -> A0
    gemm_bf16<0,0,ushort,ushort><<<dim3(512), blk, 0, stream>>>(A0, Wp(11), Bp(11), (const ushort*)nullptr, A1, 1024); // h3 -> A1

    // --- self attention 2 ---
    gemm256<1><<<dim3(384), blk5, 0, stream>>>(A1, Wp(12), Bp(12), R0, 3072, A0, 2048);
    attn_fwd<0><<<dim3(1024), blk, 0, stream>>>(R0, R0 + 1024, A0, nullptr, A1, 3072, SA_SCALE);   // -> A1
    gemm_bf16<0,0,ushort,float><<<dim3(512), blk, 0, stream>>>(A1, Wp(15), Bp(15), (const ushort*)nullptr, (float*)d_out, 1024);
}

// Round 8
// 1668.651 us; speedup vs baseline: 1.0076x; 1.0076x over previous
//
#include <hip/hip_runtime.h>
#include <cstdint>
#include <cstddef>

#define DI __device__ __forceinline__

typedef __bf16 bf16x8 __attribute__((ext_vector_type(8)));
typedef float  f32x4  __attribute__((ext_vector_type(4)));

constexpr int kE = 1024;
constexpr int kM = 8192;
constexpr float kSlope = 0.01f;

DI float bf2f(ushort u) { union { uint32_t i; float f; } v; v.i = ((uint32_t)u) << 16; return v.f; }
DI ushort f2bf(float f) {
    union { float f; uint32_t i; } v; v.f = f;
    return (ushort)((v.i + 0x7FFFu + ((v.i >> 16) & 1u)) >> 16);
}
DI bf16x8 ld8f(const float* p) {
    const float4 f0 = *(const float4*)p;
    const float4 f1 = *(const float4*)(p + 4);
    union { bf16x8 v; ushort u[8]; } o;
    o.u[0] = f2bf(f0.x); o.u[1] = f2bf(f0.y); o.u[2] = f2bf(f0.z); o.u[3] = f2bf(f0.w);
    o.u[4] = f2bf(f1.x); o.u[5] = f2bf(f1.y); o.u[6] = f2bf(f1.z); o.u[7] = f2bf(f1.w);
    return o.v;
}
template<typename T> DI float ldf(const T* p);
template<> DI float ldf<ushort>(const ushort* p) { return bf2f(*p); }
template<> DI float ldf<float>(const float* p) { return *p; }

DI void gload16(const void* g, void* lds) {
    __builtin_amdgcn_global_load_lds((const __attribute__((address_space(1))) void*)g,
                                     (__attribute__((address_space(3))) void*)lds, 16, 0, 0);
}

// XOR swizzle helper (16B-slot granularity on bits 4..6)
DI int swz7(int r) { return ((r ^ (r >> 3)) & 7) << 4; }

// ---------------------------------------------------------------------------
// cvt_pack: fp32 weights -> packed bf16 WB; x,y -> bf16; biases -> packed fp32
// ---------------------------------------------------------------------------
struct PtrTab { const float* w[16]; const float* b[16]; const float* x; const float* y; };

__global__ __launch_bounds__(256)
void cvt_pack(PtrTab t, ushort* __restrict__ WB, ushort* __restrict__ Xb,
              ushort* __restrict__ Yb, float* __restrict__ BP)
{
    const int blk = blockIdx.x, tid = threadIdx.x;
    if (blk < 16384) {
        const float* src; ushort* dst; size_t idx;
        if (blk < 8192)       { const int w = blk >> 9; idx = (size_t)(blk & 511) * 2048 + tid * 8; src = t.w[w]; dst = WB + (size_t)w * 1048576; }
        else if (blk < 12288) { idx = (size_t)(blk - 8192) * 2048 + tid * 8;  src = t.x; dst = Xb; }
        else                  { idx = (size_t)(blk - 12288) * 2048 + tid * 8; src = t.y; dst = Yb; }
        *(bf16x8*)(dst + idx) = ld8f(src + idx);
    } else {
        const size_t i = (size_t)(blk - 16384) * 2048 + tid * 8;
        const int w = (int)(i >> 10), off = (int)(i & 1023);
        *(float4*)(BP + i)     = *(const float4*)(t.b[w] + off);
        *(float4*)(BP + i + 4) = *(const float4*)(t.b[w] + off + 4);
    }
}

// ---------------------------------------------------------------------------
// 128x128-tile bf16 GEMM (narrow N): out[8192,N] = epi(A @ W^T + bias)
// BK=32, 4 waves(2x2), global_load_lds staging, double-buffered.
// ---------------------------------------------------------------------------
template<int ACT, int RESID, typename TR, typename TO>
__global__ __launch_bounds__(256)
void gemm_bf16(const ushort* __restrict__ A, const ushort* __restrict__ W,
               const float* __restrict__ bias, const TR* __restrict__ resb,
               TO* __restrict__ out, int N)
{
    __shared__ __align__(16) char sm[2][16384];   // [buf][A 8K | W 8K]
    constexpr int K = 1024;
    const int tid = threadIdx.x, l = tid & 63, wid = tid >> 6;
    const int wm = wid >> 1, wn = wid & 1;

    const int cpx = gridDim.x >> 3;
    const int sb = (blockIdx.x & 7) * cpx + (blockIdx.x >> 3);
    const int nbn = N >> 7;
    const int bm = sb / nbn, bn = sb - bm * nbn;
    const size_t row0 = (size_t)bm << 7, col0 = (size_t)bn << 7;

    // staging source precompute: o = (wid*2+i)*1024 + l*16
    const int o0 = (wid * 2) * 1024 + (l << 4), o1 = o0 + 1024;
    const int r0s = o0 >> 6, c0s = ((o0 >> 4) & 3) ^ ((r0s >> 1) & 3);
    const int r1s = o1 >> 6, c1s = ((o1 >> 4) & 3) ^ ((r1s >> 1) & 3);
    const ushort* gA0 = A + (row0 + r0s) * K + c0s * 8;
    const ushort* gA1 = A + (row0 + r1s) * K + c1s * 8;
    const ushort* gW0 = W + (col0 + r0s) * K + c0s * 8;
    const ushort* gW1 = W + (col0 + r1s) * K + c1s * 8;
    const int d0 = (wid * 2) * 1024, d1 = d0 + 1024;

    f32x4 acc[4][4] = {};

    { // prologue: stage tile 0
        gload16(gA0, sm[0] + d0); gload16(gA1, sm[0] + d1);
        gload16(gW0, sm[0] + 8192 + d0); gload16(gW1, sm[0] + 8192 + d1);
    }
    __syncthreads();

    for (int kt = 0; kt < 32; ++kt) {
        const int cur = kt & 1;
        if (kt + 1 < 32) {
            const int ko = (kt + 1) << 5;
            char* nb = sm[cur ^ 1];
            gload16(gA0 + ko, nb + d0); gload16(gA1 + ko, nb + d1);
            gload16(gW0 + ko, nb + 8192 + d0); gload16(gW1 + ko, nb + 8192 + d1);
        }
        const char* At = sm[cur];
        const char* Wt = sm[cur] + 8192;
        bf16x8 af[4], bfr[4];
        #pragma unroll
        for (int mi = 0; mi < 4; ++mi) {
            const int r = (wm << 6) + (mi << 4) + (l & 15);
            af[mi] = *(const bf16x8*)(At + r * 64 + ((((l >> 4) ^ ((r >> 1) & 3))) << 4));
        }
        #pragma unroll
        for (int ni = 0; ni < 4; ++ni) {
            const int r = (wn << 6) + (ni << 4) + (l & 15);
            bfr[ni] = *(const bf16x8*)(Wt + r * 64 + ((((l >> 4) ^ ((r >> 1) & 3))) << 4));
        }
        #pragma unroll
        for (int mi = 0; mi < 4; ++mi)
            #pragma unroll
            for (int ni = 0; ni < 4; ++ni)
                acc[mi][ni] = __builtin_amdgcn_mfma_f32_16x16x32_bf16(af[mi], bfr[ni], acc[mi][ni], 0, 0, 0);
        __syncthreads();
    }

    // epilogue: C/D layout col=lane&15, row=(lane>>4)*4+reg
    const int cr = (l >> 4) << 2, cc = l & 15;
    #pragma unroll
    for (int mi = 0; mi < 4; ++mi) {
        #pragma unroll
        for (int ni = 0; ni < 4; ++ni) {
            const size_t gr = row0 + (wm << 6) + (mi << 4) + cr;
            const size_t gc = col0 + (wn << 6) + (ni << 4) + cc;
            const float bv = bias[gc];
            #pragma unroll
            for (int r = 0; r < 4; ++r) {
                float v = acc[mi][ni][r] + bv;
                if (ACT) v = v > 0.f ? v : v * kSlope;
                const size_t off = (gr + r) * (size_t)N + gc;
                if (RESID) v += ldf(resb + off);
                if constexpr (sizeof(TO) == 4) out[off] = v;
                else                           out[off] = f2bf(v);
            }
        }
    }
}

// ---------------------------------------------------------------------------
// 256x256-tile bf16 GEMM (wide N): BK=32, 8 waves (2M x 4N), per-wave 128x64,
// double-buffered LDS, global_load_lds staging.
// Round-6/7 post-mortem: with 64 KB LDS the backend's occupancy heuristic
// targets 2 blocks/CU (4 waves/SIMD) and caps VGPR at 128 -> acc spills to
// scratch (WRITE_SIZE 1.1 GB/dispatch, MfmaUtil 4.4%). launch_bounds' 2nd arg
// (a MINIMUM) cannot raise the budget. Force a 256-VGPR budget two ways:
//   1. amdgpu_waves_per_eu(2,2): max 2 waves/EU -> 512/2 = 256 VGPRs.
//   2. 96 KB static LDS (3rd buffer unused): only 1 block/CU can be resident,
//      so the occupancy heuristic itself cannot justify a cap below 256.
// VT mode (col0 >= vtcol0): swapped-operand MFMA -> C^T, transposed store to
// vt_out[(b*1024 + d)*1024 + t] for attention's pre-transposed V.
// ---------------------------------------------------------------------------
template<int VT>
__global__ __launch_bounds__(512)
__attribute__((amdgpu_waves_per_eu(2, 2)))
void gemm256(const ushort* __restrict__ A, const ushort* __restrict__ W,
             const float* __restrict__ bias, ushort* __restrict__ out, int N,
             ushort* __restrict__ vt_out, int vtcol0)
{
    __shared__ __align__(16) char sm[3][32768];   // [buf][A 16K | W 16K]; buf2 = occupancy pad
    constexpr int K = 1024;
    const int tid = threadIdx.x, l = tid & 63, wid = tid >> 6;
    const int wm = wid >> 2, wn = wid & 3;

    const int cpx = gridDim.x >> 3;
    const int sb = (blockIdx.x & 7) * cpx + (blockIdx.x >> 3);
    const int nbn = N >> 8;
    const int bm = sb / nbn, bn = sb - bm * nbn;
    const size_t row0 = (size_t)bm << 8, col0 = (size_t)bn << 8;
    const bool isvt = VT && ((int)col0 >= vtcol0);

    // staging: slot s = tid covers rows 0..127, slot tid+512 rows 128..255.
    // row r = s>>2 (64B rows), chunk c = (s&3) ^ ((r>>1)&3).
    const int r0s = tid >> 2, c0s = (tid & 3) ^ ((r0s >> 1) & 3);
    const ushort* gA0 = A + (row0 + r0s) * K + c0s * 8;
    const ushort* gA1 = gA0 + (size_t)128 * K;     // (r0s+128): same chunk xor
    const ushort* gW0 = W + (col0 + r0s) * K + c0s * 8;
    const ushort* gW1 = gW0 + (size_t)128 * K;
    const int d0 = wid * 1024;                     // wave-uniform LDS base

    f32x4 acc[8][4] = {};

    gload16(gA0, sm[0] + d0);          gload16(gA1, sm[0] + 8192 + d0);
    gload16(gW0, sm[0] + 16384 + d0);  gload16(gW1, sm[0] + 24576 + d0);
    __syncthreads();

    for (int kt = 0; kt < 32; ++kt) {
        const int cur = kt & 1;
        if (kt + 1 < 32) {
            const int ko = (kt + 1) << 5;
            char* nb = sm[cur ^ 1];
            gload16(gA0 + ko, nb + d0);          gload16(gA1 + ko, nb + 8192 + d0);
            gload16(gW0 + ko, nb + 16384 + d0);  gload16(gW1 + ko, nb + 24576 + d0);
        }
        const char* At = sm[cur];
        const char* Wt = sm[cur] + 16384;
        bf16x8 af[8], bfr[4];
        #pragma unroll
        for (int mi = 0; mi < 8; ++mi) {
            const int r = (wm << 7) + (mi << 4) + (l & 15);
            af[mi] = *(const bf16x8*)(At + r * 64 + (((l >> 4) ^ ((r >> 1) & 3)) << 4));
        }
        #pragma unroll
        for (int ni = 0; ni < 4; ++ni) {
            const int r = (wn << 6) + (ni << 4) + (l & 15);
            bfr[ni] = *(const bf16x8*)(Wt + r * 64 + (((l >> 4) ^ ((r >> 1) & 3)) << 4));
        }
        if (!isvt) {
            #pragma unroll
            for (int mi = 0; mi < 8; ++mi)
                #pragma unroll
                for (int ni = 0; ni < 4; ++ni)
                    acc[mi][ni] = __builtin_amdgcn_mfma_f32_16x16x32_bf16(af[mi], bfr[ni], acc[mi][ni], 0, 0, 0);
        } else {
            #pragma unroll
            for (int mi = 0; mi < 8; ++mi)
                #pragma unroll
                for (int ni = 0; ni < 4; ++ni)
                    acc[mi][ni] = __builtin_amdgcn_mfma_f32_16x16x32_bf16(bfr[ni], af[mi], acc[mi][ni], 0, 0, 0);
        }
        __syncthreads();
    }

    const int cr = (l >> 4) << 2, cc = l & 15;
    if (!isvt) {
        #pragma unroll
        for (int mi = 0; mi < 8; ++mi) {
            #pragma unroll
            for (int ni = 0; ni < 4; ++ni) {
                const size_t gr = row0 + (wm << 7) + (mi << 4) + cr;
                const size_t gc = col0 + (wn << 6) + (ni << 4) + cc;
                const float bv = bias[gc];
                #pragma unroll
                for (int r = 0; r < 4; ++r) {
                    const float v = acc[mi][ni][r] + bv;
                    out[(gr + r) * (size_t)N + gc] = f2bf(v);
                }
            }
        }
    } else if (VT) {
        #pragma unroll
        for (int mi = 0; mi < 8; ++mi) {
            const size_t t_glob = row0 + (wm << 7) + (mi << 4) + cc;
            const size_t bb = t_glob >> 10;
            const int tt = (int)(t_glob & 1023);
            #pragma unroll
            for (int ni = 0; ni < 4; ++ni) {
                const int gcb = (int)col0 + (wn << 6) + (ni << 4) + cr;
                const int dbase = gcb - vtcol0;
                #pragma unroll
                for (int r = 0; r < 4; ++r) {
                    const float v = acc[mi][ni][r] + bias[gcb + r];
                    vt_out[(((bb << 10) + dbase + r) << 10) + tt] = f2bf(v);
                }
            }
        }
    }
}

// ---------------------------------------------------------------------------
// Flash attention. One block = (b, h, 64 q-rows); 4 waves x 16 q-rows.
// Q/K/QV bf16 row stride ld; V comes PRE-TRANSPOSED: VT[(b*8+h)*128+d][1024 t].
// K staged row-major [64][128]bf16 (XOR-swz) via reg->LDS uint4 stores;
// V staged [128 d][64 t] via uint4 stores (XOR-swz), PV B-frags contiguous
// ds_read_b128. P re-laid-out via per-wave LDS. Output stride 1024.
// ---------------------------------------------------------------------------
template<int ADD_QV>
__global__ __launch_bounds__(256)
void attn_fwd(const ushort* __restrict__ Q, const ushort* __restrict__ K,
              const ushort* __restrict__ VT, const ushort* __restrict__ QV,
              ushort* __restrict__ O, int ld, float scale)
{
    __shared__ __align__(16) char Kt[64 * 256];    // 16 KiB
    __shared__ __align__(16) char Vt[128 * 128];   // 16 KiB: [d][64 t] bf16
    __shared__ __align__(16) char Pl[4][2048];     // per-wave 16x64 bf16

    const int tid = threadIdx.x;
    const int l = tid & 63, w = tid >> 6;

    const int cpx = gridDim.x >> 3;                 // 1024 blocks -> 128
    const int sb = (blockIdx.x & 7) * cpx + (blockIdx.x >> 3);
    const int qt = sb & 15;
    const int bh = sb >> 4;
    const int h = bh & 7, b = bh >> 3;

    const size_t bi = ((size_t)b << 10) * (size_t)ld + ((size_t)h << 7);
    const size_t bo = ((size_t)b << 10) * 1024 + ((size_t)h << 7);
    const size_t vtoff = ((size_t)bh) << 17;        // (b*8+h)*128*1024
    const size_t qrow0 = (size_t)(qt << 6) + (w << 4);

    // Q fragments (A-side: lane&15 = q-row, (lane>>4)*8 = k-offset)
    bf16x8 qf[4];
    #pragma unroll
    for (int kk = 0; kk < 4; ++kk)
        qf[kk] = *(const bf16x8*)(Q + bi + (qrow0 + (l & 15)) * ld + (kk << 5) + ((l >> 4) << 3));

    f32x4 oacc[8] = {};
    float mrow[4] = {-1e30f, -1e30f, -1e30f, -1e30f};
    float lrow[4] = {0.f, 0.f, 0.f, 0.f};

    const int sr = tid >> 4, sc = tid & 15;   // K staging: row group / 16B chunk

    // V staging precompute (kt0-independent): LDS slot S=it*256+tid -> (d=S>>3, s=S&7)
    int vofs[4];
    #pragma unroll
    for (int it = 0; it < 4; ++it) {
        const int d = it * 32 + (tid >> 3);
        const int s = tid & 7;
        const int c = s ^ ((d ^ (d >> 3)) & 7);
        vofs[it] = d * 1024 + c * 8;
    }
    const int vdst = tid * 16;

    for (int kt0 = 0; kt0 < 16; ++kt0) {
        __syncthreads();                      // previous tile's LDS reads done
        #pragma unroll
        for (int it = 0; it < 4; ++it) {
            const int r = sr + (it << 4);     // key row 0..63
            uint4 kv = *(const uint4*)(K + bi + (size_t)(kt0 * 64 + r) * ld + (sc << 3));
            *(uint4*)(Kt + r * 256 + ((sc << 4) ^ swz7(r))) = kv;
        }
        #pragma unroll
        for (int it = 0; it < 4; ++it) {
            uint4 vv = *(const uint4*)(VT + vtoff + (size_t)(kt0 << 6) + vofs[it]);
            *(uint4*)(Vt + it * 4096 + vdst) = vv;
        }
        __syncthreads();

        // S = Q K^T  (lane holds S[q=(l>>4)*4+r][t=(l&15)+16*ni])
        f32x4 sacc[4] = {};
        #pragma unroll
        for (int ni = 0; ni < 4; ++ni) {
            const int r = (l & 15) + (ni << 4);
            #pragma unroll
            for (int kk = 0; kk < 4; ++kk) {
                bf16x8 kf = *(const bf16x8*)(Kt + r * 256 + ((((kk << 2) + (l >> 4)) << 4) ^ swz7(r)));
                sacc[ni] = __builtin_amdgcn_mfma_f32_16x16x32_bf16(qf[kk], kf, sacc[ni], 0, 0, 0);
            }
        }
        #pragma unroll
        for (int ni = 0; ni < 4; ++ni) sacc[ni] *= scale;

        // online softmax (rows reduced across the 16-lane subgroup)
        float corr[4];
        #pragma unroll
        for (int r = 0; r < 4; ++r) {
            float m0 = fmaxf(fmaxf(sacc[0][r], sacc[1][r]), fmaxf(sacc[2][r], sacc[3][r]));
            #pragma unroll
            for (int m = 1; m < 16; m <<= 1) m0 = fmaxf(m0, __shfl_xor(m0, m, 64));
            const float mn = fmaxf(mrow[r], m0);
            corr[r] = __expf(mrow[r] - mn);
            mrow[r] = mn;
        }
        float ps[4] = {0.f, 0.f, 0.f, 0.f};
        ushort pb[4][4];
        #pragma unroll
        for (int ni = 0; ni < 4; ++ni)
            #pragma unroll
            for (int r = 0; r < 4; ++r) {
                const float p = __expf(sacc[ni][r] - mrow[r]);
                ps[r] += p;
                pb[ni][r] = f2bf(p);
            }
        #pragma unroll
        for (int r = 0; r < 4; ++r) {
            float s = ps[r];
            #pragma unroll
            for (int m = 1; m < 16; m <<= 1) s += __shfl_xor(s, m, 64);
            lrow[r] = lrow[r] * corr[r] + s;
        }
        #pragma unroll
        for (int nd = 0; nd < 8; ++nd)
            #pragma unroll
            for (int r = 0; r < 4; ++r) oacc[nd][r] *= corr[r];

        // P -> per-wave LDS (re-layout to A-fragment), then PV
        char* pw = Pl[w];
        #pragma unroll
        for (int ni = 0; ni < 4; ++ni)
            #pragma unroll
            for (int r = 0; r < 4; ++r) {
                const int q = ((l >> 4) << 2) + r;
                const int t = (l & 15) + (ni << 4);
                *(ushort*)(pw + q * 128 + ((t * 2) ^ swz7(q))) = pb[ni][r];
            }
        #pragma unroll
        for (int tg = 0; tg < 2; ++tg) {
            const int q = l & 15;
            bf16x8 pf = *(const bf16x8*)(pw + q * 128 + ((((tg << 2) + (l >> 4)) << 4) ^ swz7(q)));
            #pragma unroll
            for (int nd = 0; nd < 8; ++nd) {
                const int d = (nd << 4) + (l & 15);
                const int m = (d ^ (d >> 3)) & 7;
                bf16x8 vf = *(const bf16x8*)(Vt + d * 128 + ((((tg << 2) + (l >> 4)) ^ m) << 4));
                oacc[nd] = __builtin_amdgcn_mfma_f32_16x16x32_bf16(pf, vf, oacc[nd], 0, 0, 0);
            }
        }
    }

    // epilogue: O /= l  (+ qv), bf16 store
    const size_t orow = qrow0 + ((l >> 4) << 2);
    #pragma unroll
    for (int r = 0; r < 4; ++r) {
        const float inv = 1.f / lrow[r];
        #pragma unroll
        for (int nd = 0; nd < 8; ++nd) {
            const size_t c = (l & 15) + (nd << 4);
            float v = oacc[nd][r] * inv;
            if (ADD_QV) v += bf2f(QV[bi + (orow + r) * ld + c]);
            O[bo + (orow + r) * 1024 + c] = f2bf(v);
        }
    }
}

// ---------------------------------------------------------------------------
// LayerNorm over (S,E) per batch on bf16 h1.
// ---------------------------------------------------------------------------
__global__ void ln_partial(const ushort* __restrict__ h1, float2* __restrict__ part)
{
    __shared__ float sa[8];
    const size_t off = ((size_t)blockIdx.x) << 15;
    float s = 0.f, s2 = 0.f;
    for (int i = threadIdx.x; i < 4096; i += 256) {
        uint4 u = *(const uint4*)(h1 + off + (size_t)i * 8);
        const ushort* e = (const ushort*)&u;
        #pragma unroll
        for (int j = 0; j < 8; ++j) { const float v = bf2f(e[j]); s += v; s2 += v * v; }
    }
    #pragma unroll
    for (int m = 1; m < 64; m <<= 1) { s += __shfl_xor(s, m, 64); s2 += __shfl_xor(s2, m, 64); }
    const int w = threadIdx.x >> 6;
    if ((threadIdx.x & 63) == 0) { sa[w * 2] = s; sa[w * 2 + 1] = s2; }
    __syncthreads();
    if (threadIdx.x == 0)
        part[blockIdx.x] = make_float2(sa[0] + sa[2] + sa[4] + sa[6], sa[1] + sa[3] + sa[5] + sa[7]);
}

__global__ void ln_finish(const float2* __restrict__ part, float2* __restrict__ stats)
{
    const int b = threadIdx.x;
    if (b < 8) {
        float s = 0.f, s2 = 0.f;
        for (int c = 0; c < 32; ++c) { const float2 v = part[b * 32 + c]; s += v.x; s2 += v.y; }
        const float mu = s * (1.f / 1048576.f);
        const float var = s2 * (1.f / 1048576.f) - mu * mu;
        stats[b] = make_float2(mu, rsqrtf(var + 1e-5f));
    }
}

__global__ void ln_apply(const ushort* __restrict__ h1, const float2* __restrict__ stats,
                         const float* __restrict__ gw, const float* __restrict__ gb,
                         ushort* __restrict__ hn)
{
    const size_t i = ((size_t)blockIdx.x * 256 + threadIdx.x) * 8;
    const int b = (int)(i >> 20);
    const size_t r = i & 1048575;
    const float2 st = stats[b];
    uint4 uv = *(const uint4*)(h1 + i);
    const float4 w0 = *(const float4*)(gw + r);
    const float4 w1 = *(const float4*)(gw + r + 4);
    const float4 b0 = *(const float4*)(gb + r);
    const float4 b1 = *(const float4*)(gb + r + 4);
    const float wv[8] = {w0.x, w0.y, w0.z, w0.w, w1.x, w1.y, w1.z, w1.w};
    const float bv[8] = {b0.x, b0.y, b0.z, b0.w, b1.x, b1.y, b1.z, b1.w};
    const ushort* ev = (const ushort*)&uv;
    ushort o[8];
    #pragma unroll
    for (int j = 0; j < 8; ++j)
        o[j] = f2bf((bf2f(ev[j]) - st.x) * st.y * wv[j] + bv[j]);
    *(uint4*)(hn + i) = *(const uint4*)o;
}

// ---------------------------------------------------------------------------
extern "C" void kernel_launch(void* const* d_in, const int* in_sizes, int n_in,
                              void* d_out, int out_size, void* d_ws, size_t ws_size,
                              hipStream_t stream)
{
    (void)in_sizes; (void)n_in; (void)out_size; (void)ws_size;
    auto P = [&](int i) { return (const float*)d_in[i]; };

    const size_t MB = 1u << 20;
    char* ws = (char*)d_ws;
    ushort* WB = (ushort*)ws;                       // 32 MB packed bf16 weights
    ushort* R0 = (ushort*)(ws + 32 * MB);           // 32 MB (48 MB during SA)
    ushort* R1 = (ushort*)(ws + 64 * MB);           // 32 MB
    ushort* A0 = (ushort*)(ws + 96 * MB);           // 16 MB
    ushort* A1 = (ushort*)(ws + 112 * MB);          // 16 MB
    float*  BP = (float*)(ws + 128 * MB);           // 64 KB packed fp32 biases
    float2* PART = (float2*)(ws + 128 * MB + 65536);
    float2* STATS = PART + 256;

    PtrTab tab;
    const int wsrc[16] = {2,4,6,8,10,14,16,18,20,22,24,26,28,30,32,34};
    for (int i = 0; i < 16; ++i) { tab.w[i] = P(wsrc[i]); tab.b[i] = P(wsrc[i] + 1); }
    tab.x = P(0); tab.y = P(1);

    const dim3 blk(256), blk5(512);
    const float SA_SCALE = 0.08838834764831845f;    // 1/sqrt(128)
    auto Wp = [&](int w) { return WB + (size_t)w * 1048576; };
    auto Bp = [&](int w) { return BP + (size_t)w * 1024; };

    cvt_pack<<<dim3(16392), blk, 0, stream>>>(tab, WB, A0, A1, BP);

    // --- cross attention ---
    // q|qv -> R0 (stride 2048)
    gemm256<0><<<dim3(256), blk5, 0, stream>>>(A0, Wp(0), Bp(0), R0, 2048, nullptr, 0);
    // k -> R1 (stride 2048, cols 0..1023); kv^T -> A0 (VT layout)
    gemm256<1><<<dim3(256), blk5, 0, stream>>>(A1, Wp(2), Bp(2), R1, 2048, A0, 1024);
    attn_fwd<1><<<dim3(1024), blk, 0, stream>>>(R0, R1, A0, R0 + 1024, A1, 2048, 1.0f);            // -> A1
    // h1 = x + o(ca) -> A0
    gemm_bf16<0,1,float,ushort><<<dim3(512), blk, 0, stream>>>(A1, Wp(4), Bp(4), P(0), A0, 1024);

    // --- LayerNorm over (S,E) per batch: h1=A0 -> hn=A1 ---
    ln_partial<<<dim3(256), blk, 0, stream>>>(A0, PART);
    ln_finish<<<dim3(1), dim3(64), 0, stream>>>(PART, STATS);
    ln_apply<<<dim3(4096), blk, 0, stream>>>(A0, STATS, P(12), P(13), A1);

    // --- FeedForward: hn=A1 -> h2=A0 ---
    gemm_bf16<1,0,ushort,ushort><<<dim3(512), blk, 0, stream>>>(A1, Wp(5), Bp(5), (const ushort*)nullptr, R0, 1024);
    gemm_bf16<1,0,ushort,ushort><<<dim3(512), blk, 0, stream>>>(R0, Wp(6), Bp(6), (const ushort*)nullptr, R1, 1024);
    gemm_bf16<1,1,ushort,ushort><<<dim3(512), blk, 0, stream>>>(R1, Wp(7), Bp(7), A1, A0, 1024);

    // --- self attention 1 ---
    // q|k -> R0 (stride 3072, cols 0..2047); v^T -> A1 (VT layout)
    gemm256<1><<<dim3(384), blk5, 0, stream>>>(A0, Wp(8), Bp(8), R0, 3072, A1, 2048);
    attn_fwd<0><<<dim3(1024), blk, 0, stream>>>(R0, R0 + 1024, A1, nullptr, A0, 3072, SA_SCALE);   // -> A0
    gemm_bf16<0,0,ushort,ushort><<<dim3(512), blk, 0, stream>>>(A0, Wp(11), Bp(11), (const ushort*)nullptr, A1, 1024); // h3 -> A1

    // --- self attention 2 ---
    gemm256<1><<<dim3(384), blk5, 0, stream>>>(A1, Wp(12), Bp(12), R0, 3072, A0, 2048);
    attn_fwd<0><<<dim3(1024), blk, 0, stream>>>(R0, R0 + 1024, A0, nullptr, A1, 3072, SA_SCALE);   // -> A1
    gemm_bf16<0,0,ushort,float><<<dim3(512), blk, 0, stream>>>(A1, Wp(15), Bp(15), (const ushort*)nullptr, (float*)d_out, 1024);
}

// Round 9
// 847.837 us; speedup vs baseline: 1.9830x; 1.9681x over previous
//
#include <hip/hip_runtime.h>
#include <cstdint>
#include <cstddef>

#define DI __device__ __forceinline__

typedef __bf16 bf16x8 __attribute__((ext_vector_type(8)));
typedef float  f32x4  __attribute__((ext_vector_type(4)));

constexpr int kE = 1024;
constexpr int kM = 8192;
constexpr float kSlope = 0.01f;

DI float bf2f(ushort u) { union { uint32_t i; float f; } v; v.i = ((uint32_t)u) << 16; return v.f; }
DI ushort f2bf(float f) {
    union { float f; uint32_t i; } v; v.f = f;
    return (ushort)((v.i + 0x7FFFu + ((v.i >> 16) & 1u)) >> 16);
}
DI bf16x8 ld8f(const float* p) {
    const float4 f0 = *(const float4*)p;
    const float4 f1 = *(const float4*)(p + 4);
    union { bf16x8 v; ushort u[8]; } o;
    o.u[0] = f2bf(f0.x); o.u[1] = f2bf(f0.y); o.u[2] = f2bf(f0.z); o.u[3] = f2bf(f0.w);
    o.u[4] = f2bf(f1.x); o.u[5] = f2bf(f1.y); o.u[6] = f2bf(f1.z); o.u[7] = f2bf(f1.w);
    return o.v;
}
template<typename T> DI float ldf(const T* p);
template<> DI float ldf<ushort>(const ushort* p) { return bf2f(*p); }
template<> DI float ldf<float>(const float* p) { return *p; }

DI void gload16(const void* g, void* lds) {
    __builtin_amdgcn_global_load_lds((const __attribute__((address_space(1))) void*)g,
                                     (__attribute__((address_space(3))) void*)lds, 16, 0, 0);
}

// XOR swizzle helper (16B-slot granularity on bits 4..6)
DI int swz7(int r) { return ((r ^ (r >> 3)) & 7) << 4; }

// ---------------------------------------------------------------------------
// cvt_pack: fp32 weights -> packed bf16 WB; x,y -> bf16; biases -> packed fp32
// ---------------------------------------------------------------------------
struct PtrTab { const float* w[16]; const float* b[16]; const float* x; const float* y; };

__global__ __launch_bounds__(256)
void cvt_pack(PtrTab t, ushort* __restrict__ WB, ushort* __restrict__ Xb,
              ushort* __restrict__ Yb, float* __restrict__ BP)
{
    const int blk = blockIdx.x, tid = threadIdx.x;
    if (blk < 16384) {
        const float* src; ushort* dst; size_t idx;
        if (blk < 8192)       { const int w = blk >> 9; idx = (size_t)(blk & 511) * 2048 + tid * 8; src = t.w[w]; dst = WB + (size_t)w * 1048576; }
        else if (blk < 12288) { idx = (size_t)(blk - 8192) * 2048 + tid * 8;  src = t.x; dst = Xb; }
        else                  { idx = (size_t)(blk - 12288) * 2048 + tid * 8; src = t.y; dst = Yb; }
        *(bf16x8*)(dst + idx) = ld8f(src + idx);
    } else {
        const size_t i = (size_t)(blk - 16384) * 2048 + tid * 8;
        const int w = (int)(i >> 10), off = (int)(i & 1023);
        *(float4*)(BP + i)     = *(const float4*)(t.b[w] + off);
        *(float4*)(BP + i + 4) = *(const float4*)(t.b[w] + off + 4);
    }
}

// ---------------------------------------------------------------------------
// 128x128-tile bf16 GEMM: out[8192,N] = epi(A[8192,1024] @ W[N,1024]^T + bias)
// BK=32, 4 waves(2x2), global_load_lds dwordx4 staging, double-buffered.
// SLAB SWIZZLE (round-8): block->(bm,bn) maps in slabs of 8 column-tiles
// (1024 cols, 512 blocks/slab). For N=1024 identical to the old map; for
// wide N every resident-block window touches <=8 A-panels + 8 W-panels
// (4 MB = one XCD's L2), fixing the 160 MB/dispatch L2 thrash measured at
// N=2048/3072 with the row-major map.
// VT mode (col0 >= vtcol0): swapped-operand MFMA computes C^T; epilogue
// stores transposed into vt_out[(b*1024 + d)*1024 + t] (verified round 4).
// ---------------------------------------------------------------------------
template<int ACT, int RESID, int VT, typename TR, typename TO>
__global__ __launch_bounds__(256)
void gemm_bf16(const ushort* __restrict__ A, const ushort* __restrict__ W,
               const float* __restrict__ bias, const TR* __restrict__ resb,
               TO* __restrict__ out, int N, ushort* __restrict__ vt_out, int vtcol0)
{
    __shared__ __align__(16) char sm[2][16384];   // [buf][A 8K | W 8K]
    constexpr int K = 1024;
    const int tid = threadIdx.x, l = tid & 63, wid = tid >> 6;
    const int wm = wid >> 1, wn = wid & 1;

    const int cpx = gridDim.x >> 3;
    const int sb = (blockIdx.x & 7) * cpx + (blockIdx.x >> 3);
    // slab decomposition: 512 blocks per slab = 64 row-tiles x 8 col-tiles
    const int slab = sb >> 9, rr = sb & 511;
    const int bm = rr >> 3, bn = (slab << 3) + (rr & 7);
    const size_t row0 = (size_t)bm << 7, col0 = (size_t)bn << 7;
    const bool isvt = VT && ((int)col0 >= vtcol0);

    // staging source precompute: o = (wid*2+i)*1024 + l*16
    const int o0 = (wid * 2) * 1024 + (l << 4), o1 = o0 + 1024;
    const int r0s = o0 >> 6, c0s = ((o0 >> 4) & 3) ^ ((r0s >> 1) & 3);
    const int r1s = o1 >> 6, c1s = ((o1 >> 4) & 3) ^ ((r1s >> 1) & 3);
    const ushort* gA0 = A + (row0 + r0s) * K + c0s * 8;
    const ushort* gA1 = A + (row0 + r1s) * K + c1s * 8;
    const ushort* gW0 = W + (col0 + r0s) * K + c0s * 8;
    const ushort* gW1 = W + (col0 + r1s) * K + c1s * 8;
    const int d0 = (wid * 2) * 1024, d1 = d0 + 1024;

    f32x4 acc[4][4] = {};

    { // prologue: stage tile 0
        gload16(gA0, sm[0] + d0); gload16(gA1, sm[0] + d1);
        gload16(gW0, sm[0] + 8192 + d0); gload16(gW1, sm[0] + 8192 + d1);
    }
    __syncthreads();

    for (int kt = 0; kt < 32; ++kt) {
        const int cur = kt & 1;
        if (kt + 1 < 32) {
            const int ko = (kt + 1) << 5;
            char* nb = sm[cur ^ 1];
            gload16(gA0 + ko, nb + d0); gload16(gA1 + ko, nb + d1);
            gload16(gW0 + ko, nb + 8192 + d0); gload16(gW1 + ko, nb + 8192 + d1);
        }
        const char* At = sm[cur];
        const char* Wt = sm[cur] + 8192;
        bf16x8 af[4], bfr[4];
        #pragma unroll
        for (int mi = 0; mi < 4; ++mi) {
            const int r = (wm << 6) + (mi << 4) + (l & 15);
            af[mi] = *(const bf16x8*)(At + r * 64 + ((((l >> 4) ^ ((r >> 1) & 3))) << 4));
        }
        #pragma unroll
        for (int ni = 0; ni < 4; ++ni) {
            const int r = (wn << 6) + (ni << 4) + (l & 15);
            bfr[ni] = *(const bf16x8*)(Wt + r * 64 + ((((l >> 4) ^ ((r >> 1) & 3))) << 4));
        }
        if (!isvt) {
            #pragma unroll
            for (int mi = 0; mi < 4; ++mi)
                #pragma unroll
                for (int ni = 0; ni < 4; ++ni)
                    acc[mi][ni] = __builtin_amdgcn_mfma_f32_16x16x32_bf16(af[mi], bfr[ni], acc[mi][ni], 0, 0, 0);
        } else {
            // swapped operands: D' = W_tile · A_tile^T = C^T
            #pragma unroll
            for (int mi = 0; mi < 4; ++mi)
                #pragma unroll
                for (int ni = 0; ni < 4; ++ni)
                    acc[mi][ni] = __builtin_amdgcn_mfma_f32_16x16x32_bf16(bfr[ni], af[mi], acc[mi][ni], 0, 0, 0);
        }
        __syncthreads();
    }

    const int cr = (l >> 4) << 2, cc = l & 15;
    if (!isvt) {
        // epilogue: C/D layout col=lane&15, row=(lane>>4)*4+reg (m89-verified)
        #pragma unroll
        for (int mi = 0; mi < 4; ++mi) {
            #pragma unroll
            for (int ni = 0; ni < 4; ++ni) {
                const size_t gr = row0 + (wm << 6) + (mi << 4) + cr;
                const size_t gc = col0 + (wn << 6) + (ni << 4) + cc;
                const float bv = bias[gc];
                #pragma unroll
                for (int r = 0; r < 4; ++r) {
                    float v = acc[mi][ni][r] + bv;
                    if (ACT) v = v > 0.f ? v : v * kSlope;
                    const size_t off = (gr + r) * (size_t)N + gc;
                    if (RESID) v += ldf(resb + off);
                    if constexpr (sizeof(TO) == 4) out[off] = v;
                    else                           out[off] = f2bf(v);
                }
            }
        }
    } else if (VT) {
        // D'[row=d][col=t]: d = col0-vtcol0 + (wn<<6)+(ni<<4)+cr+r, t = row0 + (wm<<6)+(mi<<4)+cc
        #pragma unroll
        for (int mi = 0; mi < 4; ++mi) {
            const size_t t_glob = row0 + (wm << 6) + (mi << 4) + cc;
            const size_t bb = t_glob >> 10;
            const int tt = (int)(t_glob & 1023);
            #pragma unroll
            for (int ni = 0; ni < 4; ++ni) {
                const int gcb = (int)col0 + (wn << 6) + (ni << 4) + cr;
                const int dbase = gcb - vtcol0;
                #pragma unroll
                for (int r = 0; r < 4; ++r) {
                    const float v = acc[mi][ni][r] + bias[gcb + r];
                    vt_out[(((bb << 10) + dbase + r) << 10) + tt] = f2bf(v);
                }
            }
        }
    }
}

// ---------------------------------------------------------------------------
// Flash attention. One block = (b, h, 64 q-rows); 4 waves x 16 q-rows.
// Q/K/QV bf16 row stride ld; V comes PRE-TRANSPOSED: VT[(b*8+h)*128+d][1024 t].
// K staged row-major [64][128]bf16 (XOR-swz) via reg->LDS uint4 stores;
// V staged [128 d][64 t] via uint4 stores (XOR-swz), PV B-frags contiguous
// ds_read_b128. P re-laid-out via per-wave LDS. Output stride 1024.
// ---------------------------------------------------------------------------
template<int ADD_QV>
__global__ __launch_bounds__(256)
void attn_fwd(const ushort* __restrict__ Q, const ushort* __restrict__ K,
              const ushort* __restrict__ VT, const ushort* __restrict__ QV,
              ushort* __restrict__ O, int ld, float scale)
{
    __shared__ __align__(16) char Kt[64 * 256];    // 16 KiB
    __shared__ __align__(16) char Vt[128 * 128];   // 16 KiB: [d][64 t] bf16
    __shared__ __align__(16) char Pl[4][2048];     // per-wave 16x64 bf16

    const int tid = threadIdx.x;
    const int l = tid & 63, w = tid >> 6;

    const int cpx = gridDim.x >> 3;                 // 1024 blocks -> 128
    const int sb = (blockIdx.x & 7) * cpx + (blockIdx.x >> 3);
    const int qt = sb & 15;
    const int bh = sb >> 4;
    const int h = bh & 7, b = bh >> 3;

    const size_t bi = ((size_t)b << 10) * (size_t)ld + ((size_t)h << 7);
    const size_t bo = ((size_t)b << 10) * 1024 + ((size_t)h << 7);
    const size_t vtoff = ((size_t)bh) << 17;        // (b*8+h)*128*1024
    const size_t qrow0 = (size_t)(qt << 6) + (w << 4);

    // Q fragments (A-side: lane&15 = q-row, (lane>>4)*8 = k-offset)
    bf16x8 qf[4];
    #pragma unroll
    for (int kk = 0; kk < 4; ++kk)
        qf[kk] = *(const bf16x8*)(Q + bi + (qrow0 + (l & 15)) * ld + (kk << 5) + ((l >> 4) << 3));

    f32x4 oacc[8] = {};
    float mrow[4] = {-1e30f, -1e30f, -1e30f, -1e30f};
    float lrow[4] = {0.f, 0.f, 0.f, 0.f};

    const int sr = tid >> 4, sc = tid & 15;   // K staging: row group / 16B chunk

    // V staging precompute (kt0-independent): LDS slot S=it*256+tid -> (d=S>>3, s=S&7)
    int vofs[4];
    #pragma unroll
    for (int it = 0; it < 4; ++it) {
        const int d = it * 32 + (tid >> 3);
        const int s = tid & 7;
        const int c = s ^ ((d ^ (d >> 3)) & 7);
        vofs[it] = d * 1024 + c * 8;
    }
    const int vdst = tid * 16;

    for (int kt0 = 0; kt0 < 16; ++kt0) {
        __syncthreads();                      // previous tile's LDS reads done
        #pragma unroll
        for (int it = 0; it < 4; ++it) {
            const int r = sr + (it << 4);     // key row 0..63
            uint4 kv = *(const uint4*)(K + bi + (size_t)(kt0 * 64 + r) * ld + (sc << 3));
            *(uint4*)(Kt + r * 256 + ((sc << 4) ^ swz7(r))) = kv;
        }
        #pragma unroll
        for (int it = 0; it < 4; ++it) {
            uint4 vv = *(const uint4*)(VT + vtoff + (size_t)(kt0 << 6) + vofs[it]);
            *(uint4*)(Vt + it * 4096 + vdst) = vv;
        }
        __syncthreads();

        // S = Q K^T  (lane holds S[q=(l>>4)*4+r][t=(l&15)+16*ni])
        f32x4 sacc[4] = {};
        #pragma unroll
        for (int ni = 0; ni < 4; ++ni) {
            const int r = (l & 15) + (ni << 4);
            #pragma unroll
            for (int kk = 0; kk < 4; ++kk) {
                bf16x8 kf = *(const bf16x8*)(Kt + r * 256 + ((((kk << 2) + (l >> 4)) << 4) ^ swz7(r)));
                sacc[ni] = __builtin_amdgcn_mfma_f32_16x16x32_bf16(qf[kk], kf, sacc[ni], 0, 0, 0);
            }
        }
        #pragma unroll
        for (int ni = 0; ni < 4; ++ni) sacc[ni] *= scale;

        // online softmax (rows reduced across the 16-lane subgroup)
        float corr[4];
        #pragma unroll
        for (int r = 0; r < 4; ++r) {
            float m0 = fmaxf(fmaxf(sacc[0][r], sacc[1][r]), fmaxf(sacc[2][r], sacc[3][r]));
            #pragma unroll
            for (int m = 1; m < 16; m <<= 1) m0 = fmaxf(m0, __shfl_xor(m0, m, 64));
            const float mn = fmaxf(mrow[r], m0);
            corr[r] = __expf(mrow[r] - mn);
            mrow[r] = mn;
        }
        float ps[4] = {0.f, 0.f, 0.f, 0.f};
        ushort pb[4][4];
        #pragma unroll
        for (int ni = 0; ni < 4; ++ni)
            #pragma unroll
            for (int r = 0; r < 4; ++r) {
                const float p = __expf(sacc[ni][r] - mrow[r]);
                ps[r] += p;
                pb[ni][r] = f2bf(p);
            }
        #pragma unroll
        for (int r = 0; r < 4; ++r) {
            float s = ps[r];
            #pragma unroll
            for (int m = 1; m < 16; m <<= 1) s += __shfl_xor(s, m, 64);
            lrow[r] = lrow[r] * corr[r] + s;
        }
        #pragma unroll
        for (int nd = 0; nd < 8; ++nd)
            #pragma unroll
            for (int r = 0; r < 4; ++r) oacc[nd][r] *= corr[r];

        // P -> per-wave LDS (re-layout to A-fragment), then PV
        char* pw = Pl[w];
        #pragma unroll
        for (int ni = 0; ni < 4; ++ni)
            #pragma unroll
            for (int r = 0; r < 4; ++r) {
                const int q = ((l >> 4) << 2) + r;
                const int t = (l & 15) + (ni << 4);
                *(ushort*)(pw + q * 128 + ((t * 2) ^ swz7(q))) = pb[ni][r];
            }
        #pragma unroll
        for (int tg = 0; tg < 2; ++tg) {
            const int q = l & 15;
            bf16x8 pf = *(const bf16x8*)(pw + q * 128 + ((((tg << 2) + (l >> 4)) << 4) ^ swz7(q)));
            #pragma unroll
            for (int nd = 0; nd < 8; ++nd) {
                const int d = (nd << 4) + (l & 15);
                const int m = (d ^ (d >> 3)) & 7;
                bf16x8 vf = *(const bf16x8*)(Vt + d * 128 + ((((tg << 2) + (l >> 4)) ^ m) << 4));
                oacc[nd] = __builtin_amdgcn_mfma_f32_16x16x32_bf16(pf, vf, oacc[nd], 0, 0, 0);
            }
        }
    }

    // epilogue: O /= l  (+ qv), bf16 store
    const size_t orow = qrow0 + ((l >> 4) << 2);
    #pragma unroll
    for (int r = 0; r < 4; ++r) {
        const float inv = 1.f / lrow[r];
        #pragma unroll
        for (int nd = 0; nd < 8; ++nd) {
            const size_t c = (l & 15) + (nd << 4);
            float v = oacc[nd][r] * inv;
            if (ADD_QV) v += bf2f(QV[bi + (orow + r) * ld + c]);
            O[bo + (orow + r) * 1024 + c] = f2bf(v);
        }
    }
}

// ---------------------------------------------------------------------------
// LayerNorm over (S,E) per batch on bf16 h1.
// ---------------------------------------------------------------------------
__global__ void ln_partial(const ushort* __restrict__ h1, float2* __restrict__ part)
{
    __shared__ float sa[8];
    const size_t off = ((size_t)blockIdx.x) << 15;
    float s = 0.f, s2 = 0.f;
    for (int i = threadIdx.x; i < 4096; i += 256) {
        uint4 u = *(const uint4*)(h1 + off + (size_t)i * 8);
        const ushort* e = (const ushort*)&u;
        #pragma unroll
        for (int j = 0; j < 8; ++j) { const float v = bf2f(e[j]); s += v; s2 += v * v; }
    }
    #pragma unroll
    for (int m = 1; m < 64; m <<= 1) { s += __shfl_xor(s, m, 64); s2 += __shfl_xor(s2, m, 64); }
    const int w = threadIdx.x >> 6;
    if ((threadIdx.x & 63) == 0) { sa[w * 2] = s; sa[w * 2 + 1] = s2; }
    __syncthreads();
    if (threadIdx.x == 0)
        part[blockIdx.x] = make_float2(sa[0] + sa[2] + sa[4] + sa[6], sa[1] + sa[3] + sa[5] + sa[7]);
}

__global__ void ln_finish(const float2* __restrict__ part, float2* __restrict__ stats)
{
    const int b = threadIdx.x;
    if (b < 8) {
        float s = 0.f, s2 = 0.f;
        for (int c = 0; c < 32; ++c) { const float2 v = part[b * 32 + c]; s += v.x; s2 += v.y; }
        const float mu = s * (1.f / 1048576.f);
        const float var = s2 * (1.f / 1048576.f) - mu * mu;
        stats[b] = make_float2(mu, rsqrtf(var + 1e-5f));
    }
}

__global__ void ln_apply(const ushort* __restrict__ h1, const float2* __restrict__ stats,
                         const float* __restrict__ gw, const float* __restrict__ gb,
                         ushort* __restrict__ hn)
{
    const size_t i = ((size_t)blockIdx.x * 256 + threadIdx.x) * 8;
    const int b = (int)(i >> 20);
    const size_t r = i & 1048575;
    const float2 st = stats[b];
    uint4 uv = *(const uint4*)(h1 + i);
    const float4 w0 = *(const float4*)(gw + r);
    const float4 w1 = *(const float4*)(gw + r + 4);
    const float4 b0 = *(const float4*)(gb + r);
    const float4 b1 = *(const float4*)(gb + r + 4);
    const float wv[8] = {w0.x, w0.y, w0.z, w0.w, w1.x, w1.y, w1.z, w1.w};
    const float bv[8] = {b0.x, b0.y, b0.z, b0.w, b1.x, b1.y, b1.z, b1.w};
    const ushort* ev = (const ushort*)&uv;
    ushort o[8];
    #pragma unroll
    for (int j = 0; j < 8; ++j)
        o[j] = f2bf((bf2f(ev[j]) - st.x) * st.y * wv[j] + bv[j]);
    *(uint4*)(hn + i) = *(const uint4*)o;
}

// ---------------------------------------------------------------------------
extern "C" void kernel_launch(void* const* d_in, const int* in_sizes, int n_in,
                              void* d_out, int out_size, void* d_ws, size_t ws_size,
                              hipStream_t stream)
{
    (void)in_sizes; (void)n_in; (void)out_size; (void)ws_size;
    auto P = [&](int i) { return (const float*)d_in[i]; };

    const size_t MB = 1u << 20;
    char* ws = (char*)d_ws;
    ushort* WB = (ushort*)ws;                       // 32 MB packed bf16 weights
    ushort* R0 = (ushort*)(ws + 32 * MB);           // 32 MB (48 MB during SA)
    ushort* R1 = (ushort*)(ws + 64 * MB);           // 32 MB
    ushort* A0 = (ushort*)(ws + 96 * MB);           // 16 MB
    ushort* A1 = (ushort*)(ws + 112 * MB);          // 16 MB
    float*  BP = (float*)(ws + 128 * MB);           // 64 KB packed fp32 biases
    float2* PART = (float2*)(ws + 128 * MB + 65536);
    float2* STATS = PART + 256;

    PtrTab tab;
    const int wsrc[16] = {2,4,6,8,10,14,16,18,20,22,24,26,28,30,32,34};
    for (int i = 0; i < 16; ++i) { tab.w[i] = P(wsrc[i]); tab.b[i] = P(wsrc[i] + 1); }
    tab.x = P(0); tab.y = P(1);

    const dim3 blk(256);
    const float SA_SCALE = 0.08838834764831845f;    // 1/sqrt(128)
    auto Wp = [&](int w) { return WB + (size_t)w * 1048576; };
    auto Bp = [&](int w) { return BP + (size_t)w * 1024; };

    cvt_pack<<<dim3(16392), blk, 0, stream>>>(tab, WB, A0, A1, BP);

    // --- cross attention ---
    // q|qv -> R0 (stride 2048)
    gemm_bf16<0,0,0,ushort,ushort><<<dim3(1024), blk, 0, stream>>>(A0, Wp(0), Bp(0), (const ushort*)nullptr, R0, 2048, nullptr, 0);
    // k -> R1 (stride 2048, cols 0..1023); kv^T -> A0 (VT layout)
    gemm_bf16<0,0,1,ushort,ushort><<<dim3(1024), blk, 0, stream>>>(A1, Wp(2), Bp(2), (const ushort*)nullptr, R1, 2048, A0, 1024);
    attn_fwd<1><<<dim3(1024), blk, 0, stream>>>(R0, R1, A0, R0 + 1024, A1, 2048, 1.0f);            // -> A1
    // h1 = x + o(ca) -> A0
    gemm_bf16<0,1,0,float,ushort><<<dim3(512), blk, 0, stream>>>(A1, Wp(4), Bp(4), P(0), A0, 1024, nullptr, 0);

    // --- LayerNorm over (S,E) per batch: h1=A0 -> hn=A1 ---
    ln_partial<<<dim3(256), blk, 0, stream>>>(A0, PART);
    ln_finish<<<dim3(1), dim3(64), 0, stream>>>(PART, STATS);
    ln_apply<<<dim3(4096), blk, 0, stream>>>(A0, STATS, P(12), P(13), A1);

    // --- FeedForward: hn=A1 -> h2=A0 ---
    gemm_bf16<1,0,0,ushort,ushort><<<dim3(512), blk, 0, stream>>>(A1, Wp(5), Bp(5), (const ushort*)nullptr, R0, 1024, nullptr, 0);
    gemm_bf16<1,0,0,ushort,ushort><<<dim3(512), blk, 0, stream>>>(R0, Wp(6), Bp(6), (const ushort*)nullptr, R1, 1024, nullptr, 0);
    gemm_bf16<1,1,0,ushort,ushort><<<dim3(512), blk, 0, stream>>>(R1, Wp(7), Bp(7), A1, A0, 1024, nullptr, 0);

    // --- self attention 1 ---
    // q|k -> R0 (stride 3072, cols 0..2047); v^T -> A1 (VT layout)
    gemm_bf16<0,0,1,ushort,ushort><<<dim3(1536), blk, 0, stream>>>(A0, Wp(8), Bp(8), (const ushort*)nullptr, R0, 3072, A1, 2048);
    attn_fwd<0><<<dim3(1024), blk, 0, stream>>>(R0, R0 + 1024, A1, nullptr, A0, 3072, SA_SCALE);   // -> A0
    gemm_bf16<0,0,0,ushort,ushort><<<dim3(512), blk, 0, stream>>>(A0, Wp(11), Bp(11), (const ushort*)nullptr, A1, 1024, nullptr, 0); // h3 -> A1

    // --- self attention 2 ---
    gemm_bf16<0,0,1,ushort,ushort><<<dim3(1536), blk, 0, stream>>>(A1, Wp(12), Bp(12), (const ushort*)nullptr, R0, 3072, A0, 2048);
    attn_fwd<0><<<dim3(1024), blk, 0, stream>>>(R0, R0 + 1024, A0, nullptr, A1, 3072, SA_SCALE);   // -> A1
    gemm_bf16<0,0,0,ushort,float><<<dim3(512), blk, 0, stream>>>(A1, Wp(15), Bp(15), (const ushort*)nullptr, (float*)d_out, 1024, nullptr, 0);
}

// Round 10
// 845.511 us; speedup vs baseline: 1.9885x; 1.0028x over previous
//
#include <hip/hip_runtime.h>
#include <cstdint>
#include <cstddef>

#define DI __device__ __forceinline__

typedef __bf16 bf16x8 __attribute__((ext_vector_type(8)));
typedef float  f32x4  __attribute__((ext_vector_type(4)));

constexpr int kE = 1024;
constexpr int kM = 8192;
constexpr float kSlope = 0.01f;

DI float bf2f(ushort u) { union { uint32_t i; float f; } v; v.i = ((uint32_t)u) << 16; return v.f; }
DI ushort f2bf(float f) {
    union { float f; uint32_t i; } v; v.f = f;
    return (ushort)((v.i + 0x7FFFu + ((v.i >> 16) & 1u)) >> 16);
}
DI bf16x8 ld8f(const float* p) {
    const float4 f0 = *(const float4*)p;
    const float4 f1 = *(const float4*)(p + 4);
    union { bf16x8 v; ushort u[8]; } o;
    o.u[0] = f2bf(f0.x); o.u[1] = f2bf(f0.y); o.u[2] = f2bf(f0.z); o.u[3] = f2bf(f0.w);
    o.u[4] = f2bf(f1.x); o.u[5] = f2bf(f1.y); o.u[6] = f2bf(f1.z); o.u[7] = f2bf(f1.w);
    return o.v;
}
template<typename T> DI float ldf(const T* p);
template<> DI float ldf<ushort>(const ushort* p) { return bf2f(*p); }
template<> DI float ldf<float>(const float* p) { return *p; }

DI void gload16(const void* g, void* lds) {
    __builtin_amdgcn_global_load_lds((const __attribute__((address_space(1))) void*)g,
                                     (__attribute__((address_space(3))) void*)lds, 16, 0, 0);
}

// XOR swizzle helper (16B-slot granularity on bits 4..6)
DI int swz7(int r) { return ((r ^ (r >> 3)) & 7) << 4; }

// ---------------------------------------------------------------------------
// cvt_pack: fp32 weights -> packed bf16 WB; x,y -> bf16; biases -> packed fp32
// ---------------------------------------------------------------------------
struct PtrTab { const float* w[16]; const float* b[16]; const float* x; const float* y; };

__global__ __launch_bounds__(256)
void cvt_pack(PtrTab t, ushort* __restrict__ WB, ushort* __restrict__ Xb,
              ushort* __restrict__ Yb, float* __restrict__ BP)
{
    const int blk = blockIdx.x, tid = threadIdx.x;
    if (blk < 16384) {
        const float* src; ushort* dst; size_t idx;
        if (blk < 8192)       { const int w = blk >> 9; idx = (size_t)(blk & 511) * 2048 + tid * 8; src = t.w[w]; dst = WB + (size_t)w * 1048576; }
        else if (blk < 12288) { idx = (size_t)(blk - 8192) * 2048 + tid * 8;  src = t.x; dst = Xb; }
        else                  { idx = (size_t)(blk - 12288) * 2048 + tid * 8; src = t.y; dst = Yb; }
        *(bf16x8*)(dst + idx) = ld8f(src + idx);
    } else {
        const size_t i = (size_t)(blk - 16384) * 2048 + tid * 8;
        const int w = (int)(i >> 10), off = (int)(i & 1023);
        *(float4*)(BP + i)     = *(const float4*)(t.b[w] + off);
        *(float4*)(BP + i + 4) = *(const float4*)(t.b[w] + off + 4);
    }
}

// ---------------------------------------------------------------------------
// 128x128-tile bf16 GEMM (narrow N): out[8192,N] = epi(A @ W^T + bias)
// BK=32, 4 waves(2x2), global_load_lds staging, double-buffered, slab swizzle.
// ---------------------------------------------------------------------------
template<int ACT, int RESID, typename TR, typename TO>
__global__ __launch_bounds__(256)
void gemm_bf16(const ushort* __restrict__ A, const ushort* __restrict__ W,
               const float* __restrict__ bias, const TR* __restrict__ resb,
               TO* __restrict__ out, int N)
{
    __shared__ __align__(16) char sm[2][16384];   // [buf][A 8K | W 8K]
    constexpr int K = 1024;
    const int tid = threadIdx.x, l = tid & 63, wid = tid >> 6;
    const int wm = wid >> 1, wn = wid & 1;

    const int cpx = gridDim.x >> 3;
    const int sb = (blockIdx.x & 7) * cpx + (blockIdx.x >> 3);
    // slab decomposition: 512 blocks per slab = 64 row-tiles x 8 col-tiles
    const int slab = sb >> 9, rr = sb & 511;
    const int bm = rr >> 3, bn = (slab << 3) + (rr & 7);
    const size_t row0 = (size_t)bm << 7, col0 = (size_t)bn << 7;

    // staging source precompute: o = (wid*2+i)*1024 + l*16
    const int o0 = (wid * 2) * 1024 + (l << 4), o1 = o0 + 1024;
    const int r0s = o0 >> 6, c0s = ((o0 >> 4) & 3) ^ ((r0s >> 1) & 3);
    const int r1s = o1 >> 6, c1s = ((o1 >> 4) & 3) ^ ((r1s >> 1) & 3);
    const ushort* gA0 = A + (row0 + r0s) * K + c0s * 8;
    const ushort* gA1 = A + (row0 + r1s) * K + c1s * 8;
    const ushort* gW0 = W + (col0 + r0s) * K + c0s * 8;
    const ushort* gW1 = W + (col0 + r1s) * K + c1s * 8;
    const int d0 = (wid * 2) * 1024, d1 = d0 + 1024;

    f32x4 acc[4][4] = {};

    { // prologue: stage tile 0
        gload16(gA0, sm[0] + d0); gload16(gA1, sm[0] + d1);
        gload16(gW0, sm[0] + 8192 + d0); gload16(gW1, sm[0] + 8192 + d1);
    }
    __syncthreads();

    for (int kt = 0; kt < 32; ++kt) {
        const int cur = kt & 1;
        if (kt + 1 < 32) {
            const int ko = (kt + 1) << 5;
            char* nb = sm[cur ^ 1];
            gload16(gA0 + ko, nb + d0); gload16(gA1 + ko, nb + d1);
            gload16(gW0 + ko, nb + 8192 + d0); gload16(gW1 + ko, nb + 8192 + d1);
        }
        const char* At = sm[cur];
        const char* Wt = sm[cur] + 8192;
        bf16x8 af[4], bfr[4];
        #pragma unroll
        for (int mi = 0; mi < 4; ++mi) {
            const int r = (wm << 6) + (mi << 4) + (l & 15);
            af[mi] = *(const bf16x8*)(At + r * 64 + ((((l >> 4) ^ ((r >> 1) & 3))) << 4));
        }
        #pragma unroll
        for (int ni = 0; ni < 4; ++ni) {
            const int r = (wn << 6) + (ni << 4) + (l & 15);
            bfr[ni] = *(const bf16x8*)(Wt + r * 64 + ((((l >> 4) ^ ((r >> 1) & 3))) << 4));
        }
        #pragma unroll
        for (int mi = 0; mi < 4; ++mi)
            #pragma unroll
            for (int ni = 0; ni < 4; ++ni)
                acc[mi][ni] = __builtin_amdgcn_mfma_f32_16x16x32_bf16(af[mi], bfr[ni], acc[mi][ni], 0, 0, 0);
        __syncthreads();
    }

    // epilogue: C/D layout col=lane&15, row=(lane>>4)*4+reg
    const int cr = (l >> 4) << 2, cc = l & 15;
    #pragma unroll
    for (int mi = 0; mi < 4; ++mi) {
        #pragma unroll
        for (int ni = 0; ni < 4; ++ni) {
            const size_t gr = row0 + (wm << 6) + (mi << 4) + cr;
            const size_t gc = col0 + (wn << 6) + (ni << 4) + cc;
            const float bv = bias[gc];
            #pragma unroll
            for (int r = 0; r < 4; ++r) {
                float v = acc[mi][ni][r] + bv;
                if (ACT) v = v > 0.f ? v : v * kSlope;
                const size_t off = (gr + r) * (size_t)N + gc;
                if (RESID) v += ldf(resb + off);
                if constexpr (sizeof(TO) == 4) out[off] = v;
                else                           out[off] = f2bf(v);
            }
        }
    }
}

// ---------------------------------------------------------------------------
// 128x256-tile bf16 GEMM (wide N). 256 threads, 4 waves (2M x 2N), per-wave
// 64x128: acc[4][8] (128 VGPR) + af[4]; bfr loaded one-at-a-time interleaved
// with MFMA to keep peak pressure ~175 (m105 precedent: this tile runs
// spill-free at 256 threads). Per K-step per wave: 12 ds_read + 32 MFMA —
// 2x the MFMA-per-barrier of the 128^2 kernel (round-9: MfmaUtil 17.8%,
// latency/barrier-bound at ~470-570 TF).
// LDS: dbuf x (A 8K | W 16K) = 48 KB. Slab = 4 col-tiles (1024 cols).
// VT mode (col0 >= vtcol0): swapped-operand MFMA -> C^T, transposed store
// into vt_out[(b*1024 + d)*1024 + t] (round-4-verified formulas).
// ---------------------------------------------------------------------------
template<int VT>
__global__ __launch_bounds__(256)
void gemm_w256(const ushort* __restrict__ A, const ushort* __restrict__ W,
               const float* __restrict__ bias, ushort* __restrict__ out, int N,
               ushort* __restrict__ vt_out, int vtcol0)
{
    __shared__ __align__(16) char sm[2][24576];   // [buf][A 8K | W 16K]
    constexpr int K = 1024;
    const int tid = threadIdx.x, l = tid & 63, wid = tid >> 6;
    const int wm = wid >> 1, wn = wid & 1;

    const int cpx = gridDim.x >> 3;
    const int sb = (blockIdx.x & 7) * cpx + (blockIdx.x >> 3);
    // slab decomposition: 256 blocks per slab = 64 row-tiles x 4 col-tiles
    const int slab = sb >> 8, rr = sb & 255;
    const int bm = rr >> 2, bn = (slab << 2) + (rr & 3);
    const size_t row0 = (size_t)bm << 7, col0 = (size_t)bn << 8;
    const bool isvt = VT && ((int)col0 >= vtcol0);

    // staging: A region o in [0,8K): o = (wid*2+i)*1024 + l*16, i<2
    //          W region o in [0,16K): o = (wid*4+i)*1024 + l*16, i<4
    // r = o>>6; c = ((o>>4)&3) ^ ((r>>1)&3); +1024 in o => r+16, same c.
    const int oA = (wid * 2) * 1024 + (l << 4);
    const int rA = oA >> 6, cA = ((oA >> 4) & 3) ^ ((rA >> 1) & 3);
    const ushort* gA = A + (row0 + rA) * K + cA * 8;
    const int oW = (wid * 4) * 1024 + (l << 4);
    const int rW = oW >> 6, cW = ((oW >> 4) & 3) ^ ((rW >> 1) & 3);
    const ushort* gW = W + (col0 + rW) * K + cW * 8;

    f32x4 acc[4][8] = {};

    { // prologue: stage tile 0
        char* nb = sm[0];
        #pragma unroll
        for (int i = 0; i < 2; ++i) gload16(gA + (size_t)i * 16 * K, nb + oA + i * 1024);
        #pragma unroll
        for (int i = 0; i < 4; ++i) gload16(gW + (size_t)i * 16 * K, nb + 8192 + oW + i * 1024);
    }
    __syncthreads();

    for (int kt = 0; kt < 32; ++kt) {
        const int cur = kt & 1;
        if (kt + 1 < 32) {
            const int ko = (kt + 1) << 5;
            char* nb = sm[cur ^ 1];
            #pragma unroll
            for (int i = 0; i < 2; ++i) gload16(gA + (size_t)i * 16 * K + ko, nb + oA + i * 1024);
            #pragma unroll
            for (int i = 0; i < 4; ++i) gload16(gW + (size_t)i * 16 * K + ko, nb + 8192 + oW + i * 1024);
        }
        const char* At = sm[cur];
        const char* Wt = sm[cur] + 8192;
        bf16x8 af[4];
        #pragma unroll
        for (int mi = 0; mi < 4; ++mi) {
            const int r = (wm << 6) + (mi << 4) + (l & 15);
            af[mi] = *(const bf16x8*)(At + r * 64 + (((l >> 4) ^ ((r >> 1) & 3)) << 4));
        }
        #pragma unroll
        for (int ni = 0; ni < 8; ++ni) {
            const int r = (wn << 7) + (ni << 4) + (l & 15);
            const bf16x8 bfr = *(const bf16x8*)(Wt + r * 64 + (((l >> 4) ^ ((r >> 1) & 3)) << 4));
            if (!isvt) {
                #pragma unroll
                for (int mi = 0; mi < 4; ++mi)
                    acc[mi][ni] = __builtin_amdgcn_mfma_f32_16x16x32_bf16(af[mi], bfr, acc[mi][ni], 0, 0, 0);
            } else {
                #pragma unroll
                for (int mi = 0; mi < 4; ++mi)
                    acc[mi][ni] = __builtin_amdgcn_mfma_f32_16x16x32_bf16(bfr, af[mi], acc[mi][ni], 0, 0, 0);
            }
        }
        __syncthreads();
    }

    const int cr = (l >> 4) << 2, cc = l & 15;
    if (!isvt) {
        #pragma unroll
        for (int mi = 0; mi < 4; ++mi) {
            #pragma unroll
            for (int ni = 0; ni < 8; ++ni) {
                const size_t gr = row0 + (wm << 6) + (mi << 4) + cr;
                const size_t gc = col0 + (wn << 7) + (ni << 4) + cc;
                const float bv = bias[gc];
                #pragma unroll
                for (int r = 0; r < 4; ++r) {
                    const float v = acc[mi][ni][r] + bv;
                    out[(gr + r) * (size_t)N + gc] = f2bf(v);
                }
            }
        }
    } else if (VT) {
        // D'[row=d][col=t]: d = col0-vtcol0 + (wn<<7)+(ni<<4)+cr+r, t = row0+(wm<<6)+(mi<<4)+cc
        #pragma unroll
        for (int mi = 0; mi < 4; ++mi) {
            const size_t t_glob = row0 + (wm << 6) + (mi << 4) + cc;
            const size_t bb = t_glob >> 10;
            const int tt = (int)(t_glob & 1023);
            #pragma unroll
            for (int ni = 0; ni < 8; ++ni) {
                const int gcb = (int)col0 + (wn << 7) + (ni << 4) + cr;
                const int dbase = gcb - vtcol0;
                #pragma unroll
                for (int r = 0; r < 4; ++r) {
                    const float v = acc[mi][ni][r] + bias[gcb + r];
                    vt_out[(((bb << 10) + dbase + r) << 10) + tt] = f2bf(v);
                }
            }
        }
    }
}

// ---------------------------------------------------------------------------
// Flash attention. One block = (b, h, 64 q-rows); 4 waves x 16 q-rows.
// Q/K/QV bf16 row stride ld; V comes PRE-TRANSPOSED: VT[(b*8+h)*128+d][1024 t].
// K staged row-major [64][128]bf16 (XOR-swz) via reg->LDS uint4 stores;
// V staged [128 d][64 t] via uint4 stores (XOR-swz), PV B-frags contiguous
// ds_read_b128. P re-laid-out via per-wave LDS. Output stride 1024.
// ---------------------------------------------------------------------------
template<int ADD_QV>
__global__ __launch_bounds__(256)
void attn_fwd(const ushort* __restrict__ Q, const ushort* __restrict__ K,
              const ushort* __restrict__ VT, const ushort* __restrict__ QV,
              ushort* __restrict__ O, int ld, float scale)
{
    __shared__ __align__(16) char Kt[64 * 256];    // 16 KiB
    __shared__ __align__(16) char Vt[128 * 128];   // 16 KiB: [d][64 t] bf16
    __shared__ __align__(16) char Pl[4][2048];     // per-wave 16x64 bf16

    const int tid = threadIdx.x;
    const int l = tid & 63, w = tid >> 6;

    const int cpx = gridDim.x >> 3;                 // 1024 blocks -> 128
    const int sb = (blockIdx.x & 7) * cpx + (blockIdx.x >> 3);
    const int qt = sb & 15;
    const int bh = sb >> 4;
    const int h = bh & 7, b = bh >> 3;

    const size_t bi = ((size_t)b << 10) * (size_t)ld + ((size_t)h << 7);
    const size_t bo = ((size_t)b << 10) * 1024 + ((size_t)h << 7);
    const size_t vtoff = ((size_t)bh) << 17;        // (b*8+h)*128*1024
    const size_t qrow0 = (size_t)(qt << 6) + (w << 4);

    // Q fragments (A-side: lane&15 = q-row, (lane>>4)*8 = k-offset)
    bf16x8 qf[4];
    #pragma unroll
    for (int kk = 0; kk < 4; ++kk)
        qf[kk] = *(const bf16x8*)(Q + bi + (qrow0 + (l & 15)) * ld + (kk << 5) + ((l >> 4) << 3));

    f32x4 oacc[8] = {};
    float mrow[4] = {-1e30f, -1e30f, -1e30f, -1e30f};
    float lrow[4] = {0.f, 0.f, 0.f, 0.f};

    const int sr = tid >> 4, sc = tid & 15;   // K staging: row group / 16B chunk

    // V staging precompute (kt0-independent): LDS slot S=it*256+tid -> (d=S>>3, s=S&7)
    int vofs[4];
    #pragma unroll
    for (int it = 0; it < 4; ++it) {
        const int d = it * 32 + (tid >> 3);
        const int s = tid & 7;
        const int c = s ^ ((d ^ (d >> 3)) & 7);
        vofs[it] = d * 1024 + c * 8;
    }
    const int vdst = tid * 16;

    for (int kt0 = 0; kt0 < 16; ++kt0) {
        __syncthreads();                      // previous tile's LDS reads done
        #pragma unroll
        for (int it = 0; it < 4; ++it) {
            const int r = sr + (it << 4);     // key row 0..63
            uint4 kv = *(const uint4*)(K + bi + (size_t)(kt0 * 64 + r) * ld + (sc << 3));
            *(uint4*)(Kt + r * 256 + ((sc << 4) ^ swz7(r))) = kv;
        }
        #pragma unroll
        for (int it = 0; it < 4; ++it) {
            uint4 vv = *(const uint4*)(VT + vtoff + (size_t)(kt0 << 6) + vofs[it]);
            *(uint4*)(Vt + it * 4096 + vdst) = vv;
        }
        __syncthreads();

        // S = Q K^T  (lane holds S[q=(l>>4)*4+r][t=(l&15)+16*ni])
        f32x4 sacc[4] = {};
        #pragma unroll
        for (int ni = 0; ni < 4; ++ni) {
            const int r = (l & 15) + (ni << 4);
            #pragma unroll
            for (int kk = 0; kk < 4; ++kk) {
                bf16x8 kf = *(const bf16x8*)(Kt + r * 256 + ((((kk << 2) + (l >> 4)) << 4) ^ swz7(r)));
                sacc[ni] = __builtin_amdgcn_mfma_f32_16x16x32_bf16(qf[kk], kf, sacc[ni], 0, 0, 0);
            }
        }
        #pragma unroll
        for (int ni = 0; ni < 4; ++ni) sacc[ni] *= scale;

        // online softmax (rows reduced across the 16-lane subgroup)
        float corr[4];
        #pragma unroll
        for (int r = 0; r < 4; ++r) {
            float m0 = fmaxf(fmaxf(sacc[0][r], sacc[1][r]), fmaxf(sacc[2][r], sacc[3][r]));
            #pragma unroll
            for (int m = 1; m < 16; m <<= 1) m0 = fmaxf(m0, __shfl_xor(m0, m, 64));
            const float mn = fmaxf(mrow[r], m0);
            corr[r] = __expf(mrow[r] - mn);
            mrow[r] = mn;
        }
        float ps[4] = {0.f, 0.f, 0.f, 0.f};
        ushort pb[4][4];
        #pragma unroll
        for (int ni = 0; ni < 4; ++ni)
            #pragma unroll
            for (int r = 0; r < 4; ++r) {
                const float p = __expf(sacc[ni][r] - mrow[r]);
                ps[r] += p;
                pb[ni][r] = f2bf(p);
            }
        #pragma unroll
        for (int r = 0; r < 4; ++r) {
            float s = ps[r];
            #pragma unroll
            for (int m = 1; m < 16; m <<= 1) s += __shfl_xor(s, m, 64);
            lrow[r] = lrow[r] * corr[r] + s;
        }
        #pragma unroll
        for (int nd = 0; nd < 8; ++nd)
            #pragma unroll
            for (int r = 0; r < 4; ++r) oacc[nd][r] *= corr[r];

        // P -> per-wave LDS (re-layout to A-fragment), then PV
        char* pw = Pl[w];
        #pragma unroll
        for (int ni = 0; ni < 4; ++ni)
            #pragma unroll
            for (int r = 0; r < 4; ++r) {
                const int q = ((l >> 4) << 2) + r;
                const int t = (l & 15) + (ni << 4);
                *(ushort*)(pw + q * 128 + ((t * 2) ^ swz7(q))) = pb[ni][r];
            }
        #pragma unroll
        for (int tg = 0; tg < 2; ++tg) {
            const int q = l & 15;
            bf16x8 pf = *(const bf16x8*)(pw + q * 128 + ((((tg << 2) + (l >> 4)) << 4) ^ swz7(q)));
            #pragma unroll
            for (int nd = 0; nd < 8; ++nd) {
                const int d = (nd << 4) + (l & 15);
                const int m = (d ^ (d >> 3)) & 7;
                bf16x8 vf = *(const bf16x8*)(Vt + d * 128 + ((((tg << 2) + (l >> 4)) ^ m) << 4));
                oacc[nd] = __builtin_amdgcn_mfma_f32_16x16x32_bf16(pf, vf, oacc[nd], 0, 0, 0);
            }
        }
    }

    // epilogue: O /= l  (+ qv), bf16 store
    const size_t orow = qrow0 + ((l >> 4) << 2);
    #pragma unroll
    for (int r = 0; r < 4; ++r) {
        const float inv = 1.f / lrow[r];
        #pragma unroll
        for (int nd = 0; nd < 8; ++nd) {
            const size_t c = (l & 15) + (nd << 4);
            float v = oacc[nd][r] * inv;
            if (ADD_QV) v += bf2f(QV[bi + (orow + r) * ld + c]);
            O[bo + (orow + r) * 1024 + c] = f2bf(v);
        }
    }
}

// ---------------------------------------------------------------------------
// LayerNorm over (S,E) per batch on bf16 h1.
// ---------------------------------------------------------------------------
__global__ void ln_partial(const ushort* __restrict__ h1, float2* __restrict__ part)
{
    __shared__ float sa[8];
    const size_t off = ((size_t)blockIdx.x) << 15;
    float s = 0.f, s2 = 0.f;
    for (int i = threadIdx.x; i < 4096; i += 256) {
        uint4 u = *(const uint4*)(h1 + off + (size_t)i * 8);
        const ushort* e = (const ushort*)&u;
        #pragma unroll
        for (int j = 0; j < 8; ++j) { const float v = bf2f(e[j]); s += v; s2 += v * v; }
    }
    #pragma unroll
    for (int m = 1; m < 64; m <<= 1) { s += __shfl_xor(s, m, 64); s2 += __shfl_xor(s2, m, 64); }
    const int w = threadIdx.x >> 6;
    if ((threadIdx.x & 63) == 0) { sa[w * 2] = s; sa[w * 2 + 1] = s2; }
    __syncthreads();
    if (threadIdx.x == 0)
        part[blockIdx.x] = make_float2(sa[0] + sa[2] + sa[4] + sa[6], sa[1] + sa[3] + sa[5] + sa[7]);
}

__global__ void ln_finish(const float2* __restrict__ part, float2* __restrict__ stats)
{
    const int b = threadIdx.x;
    if (b < 8) {
        float s = 0.f, s2 = 0.f;
        for (int c = 0; c < 32; ++c) { const float2 v = part[b * 32 + c]; s += v.x; s2 += v.y; }
        const float mu = s * (1.f / 1048576.f);
        const float var = s2 * (1.f / 1048576.f) - mu * mu;
        stats[b] = make_float2(mu, rsqrtf(var + 1e-5f));
    }
}

__global__ void ln_apply(const ushort* __restrict__ h1, const float2* __restrict__ stats,
                         const float* __restrict__ gw, const float* __restrict__ gb,
                         ushort* __restrict__ hn)
{
    const size_t i = ((size_t)blockIdx.x * 256 + threadIdx.x) * 8;
    const int b = (int)(i >> 20);
    const size_t r = i & 1048575;
    const float2 st = stats[b];
    uint4 uv = *(const uint4*)(h1 + i);
    const float4 w0 = *(const float4*)(gw + r);
    const float4 w1 = *(const float4*)(gw + r + 4);
    const float4 b0 = *(const float4*)(gb + r);
    const float4 b1 = *(const float4*)(gb + r + 4);
    const float wv[8] = {w0.x, w0.y, w0.z, w0.w, w1.x, w1.y, w1.z, w1.w};
    const float bv[8] = {b0.x, b0.y, b0.z, b0.w, b1.x, b1.y, b1.z, b1.w};
    const ushort* ev = (const ushort*)&uv;
    ushort o[8];
    #pragma unroll
    for (int j = 0; j < 8; ++j)
        o[j] = f2bf((bf2f(ev[j]) - st.x) * st.y * wv[j] + bv[j]);
    *(uint4*)(hn + i) = *(const uint4*)o;
}

// ---------------------------------------------------------------------------
extern "C" void kernel_launch(void* const* d_in, const int* in_sizes, int n_in,
                              void* d_out, int out_size, void* d_ws, size_t ws_size,
                              hipStream_t stream)
{
    (void)in_sizes; (void)n_in; (void)out_size; (void)ws_size;
    auto P = [&](int i) { return (const float*)d_in[i]; };

    const size_t MB = 1u << 20;
    char* ws = (char*)d_ws;
    ushort* WB = (ushort*)ws;                       // 32 MB packed bf16 weights
    ushort* R0 = (ushort*)(ws + 32 * MB);           // 32 MB (48 MB during SA)
    ushort* R1 = (ushort*)(ws + 64 * MB);           // 32 MB
    ushort* A0 = (ushort*)(ws + 96 * MB);           // 16 MB
    ushort* A1 = (ushort*)(ws + 112 * MB);          // 16 MB
    float*  BP = (float*)(ws + 128 * MB);           // 64 KB packed fp32 biases
    float2* PART = (float2*)(ws + 128 * MB + 65536);
    float2* STATS = PART + 256;

    PtrTab tab;
    const int wsrc[16] = {2,4,6,8,10,14,16,18,20,22,24,26,28,30,32,34};
    for (int i = 0; i < 16; ++i) { tab.w[i] = P(wsrc[i]); tab.b[i] = P(wsrc[i] + 1); }
    tab.x = P(0); tab.y = P(1);

    const dim3 blk(256);
    const float SA_SCALE = 0.08838834764831845f;    // 1/sqrt(128)
    auto Wp = [&](int w) { return WB + (size_t)w * 1048576; };
    auto Bp = [&](int w) { return BP + (size_t)w * 1024; };

    cvt_pack<<<dim3(16392), blk, 0, stream>>>(tab, WB, A0, A1, BP);

    // --- cross attention ---
    // q|qv -> R0 (stride 2048)
    gemm_w256<0><<<dim3(512), blk, 0, stream>>>(A0, Wp(0), Bp(0), R0, 2048, nullptr, 0);
    // k -> R1 (stride 2048, cols 0..1023); kv^T -> A0 (VT layout)
    gemm_w256<1><<<dim3(512), blk, 0, stream>>>(A1, Wp(2), Bp(2), R1, 2048, A0, 1024);
    attn_fwd<1><<<dim3(1024), blk, 0, stream>>>(R0, R1, A0, R0 + 1024, A1, 2048, 1.0f);            // -> A1
    // h1 = x + o(ca) -> A0
    gemm_bf16<0,1,float,ushort><<<dim3(512), blk, 0, stream>>>(A1, Wp(4), Bp(4), P(0), A0, 1024);

    // --- LayerNorm over (S,E) per batch: h1=A0 -> hn=A1 ---
    ln_partial<<<dim3(256), blk, 0, stream>>>(A0, PART);
    ln_finish<<<dim3(1), dim3(64), 0, stream>>>(PART, STATS);
    ln_apply<<<dim3(4096), blk, 0, stream>>>(A0, STATS, P(12), P(13), A1);

    // --- FeedForward: hn=A1 -> h2=A0 ---
    gemm_bf16<1,0,ushort,ushort><<<dim3(512), blk, 0, stream>>>(A1, Wp(5), Bp(5), (const ushort*)nullptr, R0, 1024);
    gemm_bf16<1,0,ushort,ushort><<<dim3(512), blk, 0, stream>>>(R0, Wp(6), Bp(6), (const ushort*)nullptr, R1, 1024);
    gemm_bf16<1,1,ushort,ushort><<<dim3(512), blk, 0, stream>>>(R1, Wp(7), Bp(7), A1, A0, 1024);

    // --- self attention 1 ---
    // q|k -> R0 (stride 3072, cols 0..2047); v^T -> A1 (VT layout)
    gemm_w256<1><<<dim3(768), blk, 0, stream>>>(A0, Wp(8), Bp(8), R0, 3072, A1, 2048);
    attn_fwd<0><<<dim3(1024), blk, 0, stream>>>(R0, R0 + 1024, A1, nullptr, A0, 3072, SA_SCALE);   // -> A0
    gemm_bf16<0,0,ushort,ushort><<<dim3(512), blk, 0, stream>>>(A0, Wp(11), Bp(11), (const ushort*)nullptr, A1, 1024); // h3 -> A1

    // --- self attention 2 ---
    gemm_w256<1><<<dim3(768), blk, 0, stream>>>(A1, Wp(12), Bp(12), R0, 3072, A0, 2048);
    attn_fwd<0><<<dim3(1024), blk, 0, stream>>>(R0, R0 + 1024, A0, nullptr, A1, 3072, SA_SCALE);   // -> A1
    gemm_bf16<0,0,ushort,float><<<dim3(512), blk, 0, stream>>>(A1, Wp(15), Bp(15), (const ushort*)nullptr, (float*)d_out, 1024);
}

// Round 11
// 782.670 us; speedup vs baseline: 2.1481x; 1.0803x over previous
//
#include <hip/hip_runtime.h>
#include <cstdint>
#include <cstddef>

#define DI __device__ __forceinline__

typedef __bf16 bf16x8 __attribute__((ext_vector_type(8)));
typedef float  f32x4  __attribute__((ext_vector_type(4)));

constexpr int kE = 1024;
constexpr int kM = 8192;
constexpr float kSlope = 0.01f;

DI float bf2f(ushort u) { union { uint32_t i; float f; } v; v.i = ((uint32_t)u) << 16; return v.f; }
DI ushort f2bf(float f) {
    union { float f; uint32_t i; } v; v.f = f;
    return (ushort)((v.i + 0x7FFFu + ((v.i >> 16) & 1u)) >> 16);
}
DI bf16x8 ld8f(const float* p) {
    const float4 f0 = *(const float4*)p;
    const float4 f1 = *(const float4*)(p + 4);
    union { bf16x8 v; ushort u[8]; } o;
    o.u[0] = f2bf(f0.x); o.u[1] = f2bf(f0.y); o.u[2] = f2bf(f0.z); o.u[3] = f2bf(f0.w);
    o.u[4] = f2bf(f1.x); o.u[5] = f2bf(f1.y); o.u[6] = f2bf(f1.z); o.u[7] = f2bf(f1.w);
    return o.v;
}
template<typename T> DI float ldf(const T* p);
template<> DI float ldf<ushort>(const ushort* p) { return bf2f(*p); }
template<> DI float ldf<float>(const float* p) { return *p; }

DI void gload16(const void* g, void* lds) {
    __builtin_amdgcn_global_load_lds((const __attribute__((address_space(1))) void*)g,
                                     (__attribute__((address_space(3))) void*)lds, 16, 0, 0);
}

// XOR swizzle helper (16B-slot granularity on bits 4..6)
DI int swz7(int r) { return ((r ^ (r >> 3)) & 7) << 4; }

// ---------------------------------------------------------------------------
// cvt_pack: fp32 weights -> packed bf16 WB; x,y -> bf16; biases -> packed fp32
// ---------------------------------------------------------------------------
struct PtrTab { const float* w[16]; const float* b[16]; const float* x; const float* y; };

__global__ __launch_bounds__(256)
void cvt_pack(PtrTab t, ushort* __restrict__ WB, ushort* __restrict__ Xb,
              ushort* __restrict__ Yb, float* __restrict__ BP)
{
    const int blk = blockIdx.x, tid = threadIdx.x;
    if (blk < 16384) {
        const float* src; ushort* dst; size_t idx;
        if (blk < 8192)       { const int w = blk >> 9; idx = (size_t)(blk & 511) * 2048 + tid * 8; src = t.w[w]; dst = WB + (size_t)w * 1048576; }
        else if (blk < 12288) { idx = (size_t)(blk - 8192) * 2048 + tid * 8;  src = t.x; dst = Xb; }
        else                  { idx = (size_t)(blk - 12288) * 2048 + tid * 8; src = t.y; dst = Yb; }
        *(bf16x8*)(dst + idx) = ld8f(src + idx);
    } else {
        const size_t i = (size_t)(blk - 16384) * 2048 + tid * 8;
        const int w = (int)(i >> 10), off = (int)(i & 1023);
        *(float4*)(BP + i)     = *(const float4*)(t.b[w] + off);
        *(float4*)(BP + i + 4) = *(const float4*)(t.b[w] + off + 4);
    }
}

// ---------------------------------------------------------------------------
// 128x128-tile bf16 GEMM: out[8192,1024] = epi(A[8192,1024] @ W[1024,1024]^T
// + bias). BK=32, 4 waves(2x2), global_load_lds staging, double-buffered,
// slab/XCD swizzle. All GEMMs in the model run at this exact shape (round-10
// post-mortem: one XCD's resident blocks then touch A 2MB + W 2MB = 4MB = L2,
// the best-measured configuration ~700 TF; wider N thrashes to ~458 TF).
// VT mode (col0 >= vtcol0; vtcol0=0 => whole dispatch): swapped-operand MFMA
// computes C^T; epilogue stores transposed into
// vt_out[(b*1024 + d)*1024 + t] (round-4/9-verified formulas).
// ---------------------------------------------------------------------------
template<int ACT, int RESID, int VT, typename TR, typename TO>
__global__ __launch_bounds__(256)
void gemm_bf16(const ushort* __restrict__ A, const ushort* __restrict__ W,
               const float* __restrict__ bias, const TR* __restrict__ resb,
               TO* __restrict__ out, int N, ushort* __restrict__ vt_out, int vtcol0)
{
    __shared__ __align__(16) char sm[2][16384];   // [buf][A 8K | W 8K]
    constexpr int K = 1024;
    const int tid = threadIdx.x, l = tid & 63, wid = tid >> 6;
    const int wm = wid >> 1, wn = wid & 1;

    const int cpx = gridDim.x >> 3;
    const int sb = (blockIdx.x & 7) * cpx + (blockIdx.x >> 3);
    // slab decomposition: 512 blocks per slab = 64 row-tiles x 8 col-tiles
    const int slab = sb >> 9, rr = sb & 511;
    const int bm = rr >> 3, bn = (slab << 3) + (rr & 7);
    const size_t row0 = (size_t)bm << 7, col0 = (size_t)bn << 7;
    const bool isvt = VT && ((int)col0 >= vtcol0);

    // staging source precompute: o = (wid*2+i)*1024 + l*16
    const int o0 = (wid * 2) * 1024 + (l << 4), o1 = o0 + 1024;
    const int r0s = o0 >> 6, c0s = ((o0 >> 4) & 3) ^ ((r0s >> 1) & 3);
    const int r1s = o1 >> 6, c1s = ((o1 >> 4) & 3) ^ ((r1s >> 1) & 3);
    const ushort* gA0 = A + (row0 + r0s) * K + c0s * 8;
    const ushort* gA1 = A + (row0 + r1s) * K + c1s * 8;
    const ushort* gW0 = W + (col0 + r0s) * K + c0s * 8;
    const ushort* gW1 = W + (col0 + r1s) * K + c1s * 8;
    const int d0 = (wid * 2) * 1024, d1 = d0 + 1024;

    f32x4 acc[4][4] = {};

    { // prologue: stage tile 0
        gload16(gA0, sm[0] + d0); gload16(gA1, sm[0] + d1);
        gload16(gW0, sm[0] + 8192 + d0); gload16(gW1, sm[0] + 8192 + d1);
    }
    __syncthreads();

    for (int kt = 0; kt < 32; ++kt) {
        const int cur = kt & 1;
        if (kt + 1 < 32) {
            const int ko = (kt + 1) << 5;
            char* nb = sm[cur ^ 1];
            gload16(gA0 + ko, nb + d0); gload16(gA1 + ko, nb + d1);
            gload16(gW0 + ko, nb + 8192 + d0); gload16(gW1 + ko, nb + 8192 + d1);
        }
        const char* At = sm[cur];
        const char* Wt = sm[cur] + 8192;
        bf16x8 af[4], bfr[4];
        #pragma unroll
        for (int mi = 0; mi < 4; ++mi) {
            const int r = (wm << 6) + (mi << 4) + (l & 15);
            af[mi] = *(const bf16x8*)(At + r * 64 + ((((l >> 4) ^ ((r >> 1) & 3))) << 4));
        }
        #pragma unroll
        for (int ni = 0; ni < 4; ++ni) {
            const int r = (wn << 6) + (ni << 4) + (l & 15);
            bfr[ni] = *(const bf16x8*)(Wt + r * 64 + ((((l >> 4) ^ ((r >> 1) & 3))) << 4));
        }
        if (!isvt) {
            #pragma unroll
            for (int mi = 0; mi < 4; ++mi)
                #pragma unroll
                for (int ni = 0; ni < 4; ++ni)
                    acc[mi][ni] = __builtin_amdgcn_mfma_f32_16x16x32_bf16(af[mi], bfr[ni], acc[mi][ni], 0, 0, 0);
        } else {
            // swapped operands: D' = W_tile · A_tile^T = C^T
            #pragma unroll
            for (int mi = 0; mi < 4; ++mi)
                #pragma unroll
                for (int ni = 0; ni < 4; ++ni)
                    acc[mi][ni] = __builtin_amdgcn_mfma_f32_16x16x32_bf16(bfr[ni], af[mi], acc[mi][ni], 0, 0, 0);
        }
        __syncthreads();
    }

    const int cr = (l >> 4) << 2, cc = l & 15;
    if (!isvt) {
        // epilogue: C/D layout col=lane&15, row=(lane>>4)*4+reg (m89-verified)
        #pragma unroll
        for (int mi = 0; mi < 4; ++mi) {
            #pragma unroll
            for (int ni = 0; ni < 4; ++ni) {
                const size_t gr = row0 + (wm << 6) + (mi << 4) + cr;
                const size_t gc = col0 + (wn << 6) + (ni << 4) + cc;
                const float bv = bias[gc];
                #pragma unroll
                for (int r = 0; r < 4; ++r) {
                    float v = acc[mi][ni][r] + bv;
                    if (ACT) v = v > 0.f ? v : v * kSlope;
                    const size_t off = (gr + r) * (size_t)N + gc;
                    if (RESID) v += ldf(resb + off);
                    if constexpr (sizeof(TO) == 4) out[off] = v;
                    else                           out[off] = f2bf(v);
                }
            }
        }
    } else if (VT) {
        // D'[row=d][col=t]: d = col0-vtcol0 + (wn<<6)+(ni<<4)+cr+r, t = row0 + (wm<<6)+(mi<<4)+cc
        #pragma unroll
        for (int mi = 0; mi < 4; ++mi) {
            const size_t t_glob = row0 + (wm << 6) + (mi << 4) + cc;
            const size_t bb = t_glob >> 10;
            const int tt = (int)(t_glob & 1023);
            #pragma unroll
            for (int ni = 0; ni < 4; ++ni) {
                const int gcb = (int)col0 + (wn << 6) + (ni << 4) + cr;
                const int dbase = gcb - vtcol0;
                #pragma unroll
                for (int r = 0; r < 4; ++r) {
                    const float v = acc[mi][ni][r] + bias[gcb + r];
                    vt_out[(((bb << 10) + dbase + r) << 10) + tt] = f2bf(v);
                }
            }
        }
    }
}

// ---------------------------------------------------------------------------
// Flash attention. One block = (b, h, 64 q-rows); 4 waves x 16 q-rows.
// Q/K/QV bf16 row stride ld (=1024 now); V PRE-TRANSPOSED:
// VT[(b*8+h)*128+d][1024 t]. K staged row-major [64][128]bf16 (XOR-swz) via
// reg->LDS uint4 stores; V staged [128 d][64 t] via uint4 stores (XOR-swz),
// PV B-frags contiguous ds_read_b128. P re-laid-out via per-wave LDS.
// Output stride 1024. ADD_QV adds qv (bf16, stride ld) before store.
// ---------------------------------------------------------------------------
template<int ADD_QV>
__global__ __launch_bounds__(256)
void attn_fwd(const ushort* __restrict__ Q, const ushort* __restrict__ K,
              const ushort* __restrict__ VT, const ushort* __restrict__ QV,
              ushort* __restrict__ O, int ld, float scale)
{
    __shared__ __align__(16) char Kt[64 * 256];    // 16 KiB
    __shared__ __align__(16) char Vt[128 * 128];   // 16 KiB: [d][64 t] bf16
    __shared__ __align__(16) char Pl[4][2048];     // per-wave 16x64 bf16

    const int tid = threadIdx.x;
    const int l = tid & 63, w = tid >> 6;

    const int cpx = gridDim.x >> 3;                 // 1024 blocks -> 128
    const int sb = (blockIdx.x & 7) * cpx + (blockIdx.x >> 3);
    const int qt = sb & 15;
    const int bh = sb >> 4;
    const int h = bh & 7, b = bh >> 3;

    const size_t bi = ((size_t)b << 10) * (size_t)ld + ((size_t)h << 7);
    const size_t bo = ((size_t)b << 10) * 1024 + ((size_t)h << 7);
    const size_t vtoff = ((size_t)bh) << 17;        // (b*8+h)*128*1024
    const size_t qrow0 = (size_t)(qt << 6) + (w << 4);

    // Q fragments (A-side: lane&15 = q-row, (lane>>4)*8 = k-offset)
    bf16x8 qf[4];
    #pragma unroll
    for (int kk = 0; kk < 4; ++kk)
        qf[kk] = *(const bf16x8*)(Q + bi + (qrow0 + (l & 15)) * ld + (kk << 5) + ((l >> 4) << 3));

    f32x4 oacc[8] = {};
    float mrow[4] = {-1e30f, -1e30f, -1e30f, -1e30f};
    float lrow[4] = {0.f, 0.f, 0.f, 0.f};

    const int sr = tid >> 4, sc = tid & 15;   // K staging: row group / 16B chunk

    // V staging precompute (kt0-independent): LDS slot S=it*256+tid -> (d=S>>3, s=S&7)
    int vofs[4];
    #pragma unroll
    for (int it = 0; it < 4; ++it) {
        const int d = it * 32 + (tid >> 3);
        const int s = tid & 7;
        const int c = s ^ ((d ^ (d >> 3)) & 7);
        vofs[it] = d * 1024 + c * 8;
    }
    const int vdst = tid * 16;

    for (int kt0 = 0; kt0 < 16; ++kt0) {
        __syncthreads();                      // previous tile's LDS reads done
        #pragma unroll
        for (int it = 0; it < 4; ++it) {
            const int r = sr + (it << 4);     // key row 0..63
            uint4 kv = *(const uint4*)(K + bi + (size_t)(kt0 * 64 + r) * ld + (sc << 3));
            *(uint4*)(Kt + r * 256 + ((sc << 4) ^ swz7(r))) = kv;
        }
        #pragma unroll
        for (int it = 0; it < 4; ++it) {
            uint4 vv = *(const uint4*)(VT + vtoff + (size_t)(kt0 << 6) + vofs[it]);
            *(uint4*)(Vt + it * 4096 + vdst) = vv;
        }
        __syncthreads();

        // S = Q K^T  (lane holds S[q=(l>>4)*4+r][t=(l&15)+16*ni])
        f32x4 sacc[4] = {};
        #pragma unroll
        for (int ni = 0; ni < 4; ++ni) {
            const int r = (l & 15) + (ni << 4);
            #pragma unroll
            for (int kk = 0; kk < 4; ++kk) {
                bf16x8 kf = *(const bf16x8*)(Kt + r * 256 + ((((kk << 2) + (l >> 4)) << 4) ^ swz7(r)));
                sacc[ni] = __builtin_amdgcn_mfma_f32_16x16x32_bf16(qf[kk], kf, sacc[ni], 0, 0, 0);
            }
        }
        #pragma unroll
        for (int ni = 0; ni < 4; ++ni) sacc[ni] *= scale;

        // online softmax (rows reduced across the 16-lane subgroup)
        float corr[4];
        #pragma unroll
        for (int r = 0; r < 4; ++r) {
            float m0 = fmaxf(fmaxf(sacc[0][r], sacc[1][r]), fmaxf(sacc[2][r], sacc[3][r]));
            #pragma unroll
            for (int m = 1; m < 16; m <<= 1) m0 = fmaxf(m0, __shfl_xor(m0, m, 64));
            const float mn = fmaxf(mrow[r], m0);
            corr[r] = __expf(mrow[r] - mn);
            mrow[r] = mn;
        }
        float ps[4] = {0.f, 0.f, 0.f, 0.f};
        ushort pb[4][4];
        #pragma unroll
        for (int ni = 0; ni < 4; ++ni)
            #pragma unroll
            for (int r = 0; r < 4; ++r) {
                const float p = __expf(sacc[ni][r] - mrow[r]);
                ps[r] += p;
                pb[ni][r] = f2bf(p);
            }
        #pragma unroll
        for (int r = 0; r < 4; ++r) {
            float s = ps[r];
            #pragma unroll
            for (int m = 1; m < 16; m <<= 1) s += __shfl_xor(s, m, 64);
            lrow[r] = lrow[r] * corr[r] + s;
        }
        #pragma unroll
        for (int nd = 0; nd < 8; ++nd)
            #pragma unroll
            for (int r = 0; r < 4; ++r) oacc[nd][r] *= corr[r];

        // P -> per-wave LDS (re-layout to A-fragment), then PV
        char* pw = Pl[w];
        #pragma unroll
        for (int ni = 0; ni < 4; ++ni)
            #pragma unroll
            for (int r = 0; r < 4; ++r) {
                const int q = ((l >> 4) << 2) + r;
                const int t = (l & 15) + (ni << 4);
                *(ushort*)(pw + q * 128 + ((t * 2) ^ swz7(q))) = pb[ni][r];
            }
        #pragma unroll
        for (int tg = 0; tg < 2; ++tg) {
            const int q = l & 15;
            bf16x8 pf = *(const bf16x8*)(pw + q * 128 + ((((tg << 2) + (l >> 4)) << 4) ^ swz7(q)));
            #pragma unroll
            for (int nd = 0; nd < 8; ++nd) {
                const int d = (nd << 4) + (l & 15);
                const int m = (d ^ (d >> 3)) & 7;
                bf16x8 vf = *(const bf16x8*)(Vt + d * 128 + ((((tg << 2) + (l >> 4)) ^ m) << 4));
                oacc[nd] = __builtin_amdgcn_mfma_f32_16x16x32_bf16(pf, vf, oacc[nd], 0, 0, 0);
            }
        }
    }

    // epilogue: O /= l  (+ qv), bf16 store
    const size_t orow = qrow0 + ((l >> 4) << 2);
    #pragma unroll
    for (int r = 0; r < 4; ++r) {
        const float inv = 1.f / lrow[r];
        #pragma unroll
        for (int nd = 0; nd < 8; ++nd) {
            const size_t c = (l & 15) + (nd << 4);
            float v = oacc[nd][r] * inv;
            if (ADD_QV) v += bf2f(QV[bi + (orow + r) * ld + c]);
            O[bo + (orow + r) * 1024 + c] = f2bf(v);
        }
    }
}

// ---------------------------------------------------------------------------
// LayerNorm over (S,E) per batch on bf16 h1.
// ---------------------------------------------------------------------------
__global__ void ln_partial(const ushort* __restrict__ h1, float2* __restrict__ part)
{
    __shared__ float sa[8];
    const size_t off = ((size_t)blockIdx.x) << 15;
    float s = 0.f, s2 = 0.f;
    for (int i = threadIdx.x; i < 4096; i += 256) {
        uint4 u = *(const uint4*)(h1 + off + (size_t)i * 8);
        const ushort* e = (const ushort*)&u;
        #pragma unroll
        for (int j = 0; j < 8; ++j) { const float v = bf2f(e[j]); s += v; s2 += v * v; }
    }
    #pragma unroll
    for (int m = 1; m < 64; m <<= 1) { s += __shfl_xor(s, m, 64); s2 += __shfl_xor(s2, m, 64); }
    const int w = threadIdx.x >> 6;
    if ((threadIdx.x & 63) == 0) { sa[w * 2] = s; sa[w * 2 + 1] = s2; }
    __syncthreads();
    if (threadIdx.x == 0)
        part[blockIdx.x] = make_float2(sa[0] + sa[2] + sa[4] + sa[6], sa[1] + sa[3] + sa[5] + sa[7]);
}

__global__ void ln_finish(const float2* __restrict__ part, float2* __restrict__ stats)
{
    const int b = threadIdx.x;
    if (b < 8) {
        float s = 0.f, s2 = 0.f;
        for (int c = 0; c < 32; ++c) { const float2 v = part[b * 32 + c]; s += v.x; s2 += v.y; }
        const float mu = s * (1.f / 1048576.f);
        const float var = s2 * (1.f / 1048576.f) - mu * mu;
        stats[b] = make_float2(mu, rsqrtf(var + 1e-5f));
    }
}

__global__ void ln_apply(const ushort* __restrict__ h1, const float2* __restrict__ stats,
                         const float* __restrict__ gw, const float* __restrict__ gb,
                         ushort* __restrict__ hn)
{
    const size_t i = ((size_t)blockIdx.x * 256 + threadIdx.x) * 8;
    const int b = (int)(i >> 20);
    const size_t r = i & 1048575;
    const float2 st = stats[b];
    uint4 uv = *(const uint4*)(h1 + i);
    const float4 w0 = *(const float4*)(gw + r);
    const float4 w1 = *(const float4*)(gw + r + 4);
    const float4 b0 = *(const float4*)(gb + r);
    const float4 b1 = *(const float4*)(gb + r + 4);
    const float wv[8] = {w0.x, w0.y, w0.z, w0.w, w1.x, w1.y, w1.z, w1.w};
    const float bv[8] = {b0.x, b0.y, b0.z, b0.w, b1.x, b1.y, b1.z, b1.w};
    const ushort* ev = (const ushort*)&uv;
    ushort o[8];
    #pragma unroll
    for (int j = 0; j < 8; ++j)
        o[j] = f2bf((bf2f(ev[j]) - st.x) * st.y * wv[j] + bv[j]);
    *(uint4*)(hn + i) = *(const uint4*)o;
}

// ---------------------------------------------------------------------------
extern "C" void kernel_launch(void* const* d_in, const int* in_sizes, int n_in,
                              void* d_out, int out_size, void* d_ws, size_t ws_size,
                              hipStream_t stream)
{
    (void)in_sizes; (void)n_in; (void)out_size; (void)ws_size;
    auto P = [&](int i) { return (const float*)d_in[i]; };

    const size_t MB = 1u << 20;
    char* ws = (char*)d_ws;
    ushort* WB = (ushort*)ws;                       // 32 MB packed bf16 weights
    ushort* B0 = (ushort*)(ws + 32 * MB);           // 6 x 16 MB bf16 buffers
    ushort* B1 = (ushort*)(ws + 48 * MB);
    ushort* B2 = (ushort*)(ws + 64 * MB);
    ushort* B3 = (ushort*)(ws + 80 * MB);
    ushort* B4 = (ushort*)(ws + 96 * MB);
    ushort* B5 = (ushort*)(ws + 112 * MB);
    float*  BP = (float*)(ws + 128 * MB);           // 64 KB packed fp32 biases
    float2* PART = (float2*)(ws + 128 * MB + 65536);
    float2* STATS = PART + 256;

    PtrTab tab;
    const int wsrc[16] = {2,4,6,8,10,14,16,18,20,22,24,26,28,30,32,34};
    for (int i = 0; i < 16; ++i) { tab.w[i] = P(wsrc[i]); tab.b[i] = P(wsrc[i] + 1); }
    tab.x = P(0); tab.y = P(1);

    const dim3 blk(256), gg(512);
    const float SA_SCALE = 0.08838834764831845f;    // 1/sqrt(128)
    auto Wp = [&](int w) { return WB + (size_t)w * 1048576; };
    auto Bp = [&](int w) { return BP + (size_t)w * 1024; };
    const ushort* NUS = nullptr;

    // x_bf16 -> B4, y_bf16 -> B5
    cvt_pack<<<dim3(16392), blk, 0, stream>>>(tab, WB, B4, B5, BP);

    // --- cross attention (all GEMMs N=1024) ---
    gemm_bf16<0,0,0,ushort,ushort><<<gg, blk, 0, stream>>>(B4, Wp(0), Bp(0), NUS, B0, 1024, nullptr, 0);  // q  -> B0
    gemm_bf16<0,0,0,ushort,ushort><<<gg, blk, 0, stream>>>(B4, Wp(1), Bp(1), NUS, B1, 1024, nullptr, 0);  // qv -> B1
    gemm_bf16<0,0,0,ushort,ushort><<<gg, blk, 0, stream>>>(B5, Wp(2), Bp(2), NUS, B2, 1024, nullptr, 0);  // k  -> B2
    gemm_bf16<0,0,1,ushort,ushort><<<gg, blk, 0, stream>>>(B5, Wp(3), Bp(3), NUS, B3, 1024, B3, 0);       // kv^T -> B3
    attn_fwd<1><<<dim3(1024), blk, 0, stream>>>(B0, B2, B3, B1, B4, 1024, 1.0f);                           // -> B4
    gemm_bf16<0,1,0,float,ushort><<<gg, blk, 0, stream>>>(B4, Wp(4), Bp(4), P(0), B5, 1024, nullptr, 0);   // h1 = x + o(ca) -> B5

    // --- LayerNorm over (S,E) per batch: h1=B5 -> hn=B0 ---
    ln_partial<<<dim3(256), blk, 0, stream>>>(B5, PART);
    ln_finish<<<dim3(1), dim3(64), 0, stream>>>(PART, STATS);
    ln_apply<<<dim3(4096), blk, 0, stream>>>(B5, STATS, P(12), P(13), B0);

    // --- FeedForward: hn=B0 -> h2=B3 ---
    gemm_bf16<1,0,0,ushort,ushort><<<gg, blk, 0, stream>>>(B0, Wp(5), Bp(5), NUS, B1, 1024, nullptr, 0);   // f1
    gemm_bf16<1,0,0,ushort,ushort><<<gg, blk, 0, stream>>>(B1, Wp(6), Bp(6), NUS, B2, 1024, nullptr, 0);   // f2
    gemm_bf16<1,1,0,ushort,ushort><<<gg, blk, 0, stream>>>(B2, Wp(7), Bp(7), B0, B3, 1024, nullptr, 0);    // h2 = hn + lr(f3)

    // --- self attention 1 (input h2=B3) ---
    gemm_bf16<0,0,0,ushort,ushort><<<gg, blk, 0, stream>>>(B3, Wp(8),  Bp(8),  NUS, B0, 1024, nullptr, 0); // q1 -> B0
    gemm_bf16<0,0,0,ushort,ushort><<<gg, blk, 0, stream>>>(B3, Wp(9),  Bp(9),  NUS, B1, 1024, nullptr, 0); // k1 -> B1
    gemm_bf16<0,0,1,ushort,ushort><<<gg, blk, 0, stream>>>(B3, Wp(10), Bp(10), NUS, B2, 1024, B2, 0);      // v1^T -> B2
    attn_fwd<0><<<dim3(1024), blk, 0, stream>>>(B0, B1, B2, nullptr, B4, 1024, SA_SCALE);                  // -> B4
    gemm_bf16<0,0,0,ushort,ushort><<<gg, blk, 0, stream>>>(B4, Wp(11), Bp(11), NUS, B5, 1024, nullptr, 0); // h3 -> B5

    // --- self attention 2 (input h3=B5) ---
    gemm_bf16<0,0,0,ushort,ushort><<<gg, blk, 0, stream>>>(B5, Wp(12), Bp(12), NUS, B0, 1024, nullptr, 0); // q2 -> B0
    gemm_bf16<0,0,0,ushort,ushort><<<gg, blk, 0, stream>>>(B5, Wp(13), Bp(13), NUS, B1, 1024, nullptr, 0); // k2 -> B1
    gemm_bf16<0,0,1,ushort,ushort><<<gg, blk, 0, stream>>>(B5, Wp(14), Bp(14), NUS, B2, 1024, B2, 0);      // v2^T -> B2
    attn_fwd<0><<<dim3(1024), blk, 0, stream>>>(B0, B1, B2, nullptr, B4, 1024, SA_SCALE);                  // -> B4
    gemm_bf16<0,0,0,ushort,float><<<gg, blk, 0, stream>>>(B4, Wp(15), Bp(15), NUS, (float*)d_out, 1024, nullptr, 0);
}

// Round 12
// 757.243 us; speedup vs baseline: 2.2203x; 1.0336x over previous
//
#include <hip/hip_runtime.h>
#include <cstdint>
#include <cstddef>

#define DI __device__ __forceinline__

typedef __bf16 bf16x8 __attribute__((ext_vector_type(8)));
typedef float  f32x4  __attribute__((ext_vector_type(4)));

constexpr int kE = 1024;
constexpr int kM = 8192;
constexpr float kSlope = 0.01f;

DI float bf2f(ushort u) { union { uint32_t i; float f; } v; v.i = ((uint32_t)u) << 16; return v.f; }
DI ushort f2bf(float f) {
    union { float f; uint32_t i; } v; v.f = f;
    return (ushort)((v.i + 0x7FFFu + ((v.i >> 16) & 1u)) >> 16);
}
DI bf16x8 ld8f(const float* p) {
    const float4 f0 = *(const float4*)p;
    const float4 f1 = *(const float4*)(p + 4);
    union { bf16x8 v; ushort u[8]; } o;
    o.u[0] = f2bf(f0.x); o.u[1] = f2bf(f0.y); o.u[2] = f2bf(f0.z); o.u[3] = f2bf(f0.w);
    o.u[4] = f2bf(f1.x); o.u[5] = f2bf(f1.y); o.u[6] = f2bf(f1.z); o.u[7] = f2bf(f1.w);
    return o.v;
}
template<typename T> DI float ldf(const T* p);
template<> DI float ldf<ushort>(const ushort* p) { return bf2f(*p); }
template<> DI float ldf<float>(const float* p) { return *p; }

DI void gload16(const void* g, void* lds) {
    __builtin_amdgcn_global_load_lds((const __attribute__((address_space(1))) void*)g,
                                     (__attribute__((address_space(3))) void*)lds, 16, 0, 0);
}

// XOR swizzle helper (16B-slot granularity on bits 4..6)
DI int swz7(int r) { return ((r ^ (r >> 3)) & 7) << 4; }

// ---------------------------------------------------------------------------
// cvt_pack: fp32 weights -> packed bf16 WB; x,y -> bf16; biases -> packed fp32
// ---------------------------------------------------------------------------
struct PtrTab { const float* w[16]; const float* b[16]; const float* x; const float* y; };

__global__ __launch_bounds__(256)
void cvt_pack(PtrTab t, ushort* __restrict__ WB, ushort* __restrict__ Xb,
              ushort* __restrict__ Yb, float* __restrict__ BP)
{
    const int blk = blockIdx.x, tid = threadIdx.x;
    if (blk < 16384) {
        const float* src; ushort* dst; size_t idx;
        if (blk < 8192)       { const int w = blk >> 9; idx = (size_t)(blk & 511) * 2048 + tid * 8; src = t.w[w]; dst = WB + (size_t)w * 1048576; }
        else if (blk < 12288) { idx = (size_t)(blk - 8192) * 2048 + tid * 8;  src = t.x; dst = Xb; }
        else                  { idx = (size_t)(blk - 12288) * 2048 + tid * 8; src = t.y; dst = Yb; }
        *(bf16x8*)(dst + idx) = ld8f(src + idx);
    } else {
        const size_t i = (size_t)(blk - 16384) * 2048 + tid * 8;
        const int w = (int)(i >> 10), off = (int)(i & 1023);
        *(float4*)(BP + i)     = *(const float4*)(t.b[w] + off);
        *(float4*)(BP + i + 4) = *(const float4*)(t.b[w] + off + 4);
    }
}

// ---------------------------------------------------------------------------
// 128x128-tile bf16 GEMM: out[8192,1024] = epi(A[8192,1024] @ W[1024,1024]^T
// + bias). BK=32, 4 waves(2x2), global_load_lds staging, double-buffered,
// slab/XCD swizzle. All GEMMs run at this exact shape (round-10 post-mortem:
// one XCD's resident blocks touch A 2MB + W 2MB = 4MB = L2; ~716 TF measured).
// VT mode (vtcol0=0 => whole dispatch): swapped-operand MFMA computes C^T;
// epilogue stores transposed into vt_out[(b*1024 + d)*1024 + t].
// ---------------------------------------------------------------------------
template<int ACT, int RESID, int VT, typename TR, typename TO>
__global__ __launch_bounds__(256)
void gemm_bf16(const ushort* __restrict__ A, const ushort* __restrict__ W,
               const float* __restrict__ bias, const TR* __restrict__ resb,
               TO* __restrict__ out, int N, ushort* __restrict__ vt_out, int vtcol0)
{
    __shared__ __align__(16) char sm[2][16384];   // [buf][A 8K | W 8K]
    constexpr int K = 1024;
    const int tid = threadIdx.x, l = tid & 63, wid = tid >> 6;
    const int wm = wid >> 1, wn = wid & 1;

    const int cpx = gridDim.x >> 3;
    const int sb = (blockIdx.x & 7) * cpx + (blockIdx.x >> 3);
    // slab decomposition: 512 blocks per slab = 64 row-tiles x 8 col-tiles
    const int slab = sb >> 9, rr = sb & 511;
    const int bm = rr >> 3, bn = (slab << 3) + (rr & 7);
    const size_t row0 = (size_t)bm << 7, col0 = (size_t)bn << 7;
    const bool isvt = VT && ((int)col0 >= vtcol0);

    // staging source precompute: o = (wid*2+i)*1024 + l*16
    const int o0 = (wid * 2) * 1024 + (l << 4), o1 = o0 + 1024;
    const int r0s = o0 >> 6, c0s = ((o0 >> 4) & 3) ^ ((r0s >> 1) & 3);
    const int r1s = o1 >> 6, c1s = ((o1 >> 4) & 3) ^ ((r1s >> 1) & 3);
    const ushort* gA0 = A + (row0 + r0s) * K + c0s * 8;
    const ushort* gA1 = A + (row0 + r1s) * K + c1s * 8;
    const ushort* gW0 = W + (col0 + r0s) * K + c0s * 8;
    const ushort* gW1 = W + (col0 + r1s) * K + c1s * 8;
    const int d0 = (wid * 2) * 1024, d1 = d0 + 1024;

    f32x4 acc[4][4] = {};

    { // prologue: stage tile 0
        gload16(gA0, sm[0] + d0); gload16(gA1, sm[0] + d1);
        gload16(gW0, sm[0] + 8192 + d0); gload16(gW1, sm[0] + 8192 + d1);
    }
    __syncthreads();

    for (int kt = 0; kt < 32; ++kt) {
        const int cur = kt & 1;
        if (kt + 1 < 32) {
            const int ko = (kt + 1) << 5;
            char* nb = sm[cur ^ 1];
            gload16(gA0 + ko, nb + d0); gload16(gA1 + ko, nb + d1);
            gload16(gW0 + ko, nb + 8192 + d0); gload16(gW1 + ko, nb + 8192 + d1);
        }
        const char* At = sm[cur];
        const char* Wt = sm[cur] + 8192;
        bf16x8 af[4], bfr[4];
        #pragma unroll
        for (int mi = 0; mi < 4; ++mi) {
            const int r = (wm << 6) + (mi << 4) + (l & 15);
            af[mi] = *(const bf16x8*)(At + r * 64 + ((((l >> 4) ^ ((r >> 1) & 3))) << 4));
        }
        #pragma unroll
        for (int ni = 0; ni < 4; ++ni) {
            const int r = (wn << 6) + (ni << 4) + (l & 15);
            bfr[ni] = *(const bf16x8*)(Wt + r * 64 + ((((l >> 4) ^ ((r >> 1) & 3))) << 4));
        }
        if (!isvt) {
            #pragma unroll
            for (int mi = 0; mi < 4; ++mi)
                #pragma unroll
                for (int ni = 0; ni < 4; ++ni)
                    acc[mi][ni] = __builtin_amdgcn_mfma_f32_16x16x32_bf16(af[mi], bfr[ni], acc[mi][ni], 0, 0, 0);
        } else {
            // swapped operands: D' = W_tile · A_tile^T = C^T
            #pragma unroll
            for (int mi = 0; mi < 4; ++mi)
                #pragma unroll
                for (int ni = 0; ni < 4; ++ni)
                    acc[mi][ni] = __builtin_amdgcn_mfma_f32_16x16x32_bf16(bfr[ni], af[mi], acc[mi][ni], 0, 0, 0);
        }
        __syncthreads();
    }

    const int cr = (l >> 4) << 2, cc = l & 15;
    if (!isvt) {
        // epilogue: C/D layout col=lane&15, row=(lane>>4)*4+reg (m89-verified)
        #pragma unroll
        for (int mi = 0; mi < 4; ++mi) {
            #pragma unroll
            for (int ni = 0; ni < 4; ++ni) {
                const size_t gr = row0 + (wm << 6) + (mi << 4) + cr;
                const size_t gc = col0 + (wn << 6) + (ni << 4) + cc;
                const float bv = bias[gc];
                #pragma unroll
                for (int r = 0; r < 4; ++r) {
                    float v = acc[mi][ni][r] + bv;
                    if (ACT) v = v > 0.f ? v : v * kSlope;
                    const size_t off = (gr + r) * (size_t)N + gc;
                    if (RESID) v += ldf(resb + off);
                    if constexpr (sizeof(TO) == 4) out[off] = v;
                    else                           out[off] = f2bf(v);
                }
            }
        }
    } else if (VT) {
        // D'[row=d][col=t]: d = col0-vtcol0 + (wn<<6)+(ni<<4)+cr+r, t = row0 + (wm<<6)+(mi<<4)+cc
        #pragma unroll
        for (int mi = 0; mi < 4; ++mi) {
            const size_t t_glob = row0 + (wm << 6) + (mi << 4) + cc;
            const size_t bb = t_glob >> 10;
            const int tt = (int)(t_glob & 1023);
            #pragma unroll
            for (int ni = 0; ni < 4; ++ni) {
                const int gcb = (int)col0 + (wn << 6) + (ni << 4) + cr;
                const int dbase = gcb - vtcol0;
                #pragma unroll
                for (int r = 0; r < 4; ++r) {
                    const float v = acc[mi][ni][r] + bias[gcb + r];
                    vt_out[(((bb << 10) + dbase + r) << 10) + tt] = f2bf(v);
                }
            }
        }
    }
}

// ---------------------------------------------------------------------------
// Flash attention. One block = (b, h, 64 q-rows); 4 waves x 16 q-rows.
// Q/K/QV bf16 row stride ld; V PRE-TRANSPOSED: VT[(b*8+h)*128+d][1024 t].
// Round-12 softmax-path rework (kernel was VALU-bound: 36.7% VALUBusy vs
// 13.2% MfmaUtil):
//  - row-sum via ones-MFMA: lacc = mfma(P, ones) is the softmax denominator
//    (kills the 16-shfl+16-add sum reduction per tile; numerator and
//    denominator share the same bf16 P so rounding cancels in the ratio)
//  - defer-rescale (T13, thr=0): skip corr-exp + 36 rescale mults unless a
//    row max grew (wave-uniform __any; ~21% of tiles on random data)
//  - native __bf16 casts for P (v_cvt_pk_bf16_f32, RNE) instead of 4-op RNE
//    bit-twiddle.
// ---------------------------------------------------------------------------
template<int ADD_QV>
__global__ __launch_bounds__(256)
void attn_fwd(const ushort* __restrict__ Q, const ushort* __restrict__ K,
              const ushort* __restrict__ VT, const ushort* __restrict__ QV,
              ushort* __restrict__ O, int ld, float scale)
{
    __shared__ __align__(16) char Kt[64 * 256];    // 16 KiB
    __shared__ __align__(16) char Vt[128 * 128];   // 16 KiB: [d][64 t] bf16
    __shared__ __align__(16) char Pl[4][2048];     // per-wave 16x64 bf16

    const int tid = threadIdx.x;
    const int l = tid & 63, w = tid >> 6;

    const int cpx = gridDim.x >> 3;                 // 1024 blocks -> 128
    const int sb = (blockIdx.x & 7) * cpx + (blockIdx.x >> 3);
    const int qt = sb & 15;
    const int bh = sb >> 4;
    const int h = bh & 7, b = bh >> 3;

    const size_t bi = ((size_t)b << 10) * (size_t)ld + ((size_t)h << 7);
    const size_t bo = ((size_t)b << 10) * 1024 + ((size_t)h << 7);
    const size_t vtoff = ((size_t)bh) << 17;        // (b*8+h)*128*1024
    const size_t qrow0 = (size_t)(qt << 6) + (w << 4);

    // Q fragments (A-side: lane&15 = q-row, (lane>>4)*8 = k-offset)
    bf16x8 qf[4];
    #pragma unroll
    for (int kk = 0; kk < 4; ++kk)
        qf[kk] = *(const bf16x8*)(Q + bi + (qrow0 + (l & 15)) * ld + (kk << 5) + ((l >> 4) << 3));

    f32x4 oacc[8] = {};
    f32x4 lacc = {};                                // row-sum accumulator
    float mrow[4] = {-1e30f, -1e30f, -1e30f, -1e30f};

    bf16x8 vones;
    #pragma unroll
    for (int j = 0; j < 8; ++j) vones[j] = (__bf16)1.0f;

    const int sr = tid >> 4, sc = tid & 15;   // K staging: row group / 16B chunk

    // V staging precompute (kt0-independent): LDS slot S=it*256+tid -> (d=S>>3, s=S&7)
    int vofs[4];
    #pragma unroll
    for (int it = 0; it < 4; ++it) {
        const int d = it * 32 + (tid >> 3);
        const int s = tid & 7;
        const int c = s ^ ((d ^ (d >> 3)) & 7);
        vofs[it] = d * 1024 + c * 8;
    }
    const int vdst = tid * 16;

    for (int kt0 = 0; kt0 < 16; ++kt0) {
        __syncthreads();                      // previous tile's LDS reads done
        #pragma unroll
        for (int it = 0; it < 4; ++it) {
            const int r = sr + (it << 4);     // key row 0..63
            uint4 kv = *(const uint4*)(K + bi + (size_t)(kt0 * 64 + r) * ld + (sc << 3));
            *(uint4*)(Kt + r * 256 + ((sc << 4) ^ swz7(r))) = kv;
        }
        #pragma unroll
        for (int it = 0; it < 4; ++it) {
            uint4 vv = *(const uint4*)(VT + vtoff + (size_t)(kt0 << 6) + vofs[it]);
            *(uint4*)(Vt + it * 4096 + vdst) = vv;
        }
        __syncthreads();

        // S = Q K^T  (lane holds S[q=(l>>4)*4+r][t=(l&15)+16*ni])
        f32x4 sacc[4] = {};
        #pragma unroll
        for (int ni = 0; ni < 4; ++ni) {
            const int r = (l & 15) + (ni << 4);
            #pragma unroll
            for (int kk = 0; kk < 4; ++kk) {
                bf16x8 kf = *(const bf16x8*)(Kt + r * 256 + ((((kk << 2) + (l >> 4)) << 4) ^ swz7(r)));
                sacc[ni] = __builtin_amdgcn_mfma_f32_16x16x32_bf16(qf[kk], kf, sacc[ni], 0, 0, 0);
            }
        }
        #pragma unroll
        for (int ni = 0; ni < 4; ++ni) sacc[ni] *= scale;

        // row max over the 16-lane t-groups
        float m0[4];
        #pragma unroll
        for (int r = 0; r < 4; ++r) {
            float m = fmaxf(fmaxf(sacc[0][r], sacc[1][r]), fmaxf(sacc[2][r], sacc[3][r]));
            #pragma unroll
            for (int msk = 1; msk < 16; msk <<= 1) m = fmaxf(m, __shfl_xor(m, msk, 64));
            m0[r] = m;
        }
        // defer-rescale: only when some row's max grew (wave-uniform branch)
        const bool grow = (m0[0] > mrow[0]) || (m0[1] > mrow[1]) ||
                          (m0[2] > mrow[2]) || (m0[3] > mrow[3]);
        if (__any(grow)) {
            float corr[4];
            #pragma unroll
            for (int r = 0; r < 4; ++r) {
                const float mn = fmaxf(mrow[r], m0[r]);
                corr[r] = __expf(mrow[r] - mn);
                mrow[r] = mn;
            }
            #pragma unroll
            for (int nd = 0; nd < 8; ++nd)
                #pragma unroll
                for (int r = 0; r < 4; ++r) oacc[nd][r] *= corr[r];
            #pragma unroll
            for (int r = 0; r < 4; ++r) lacc[r] *= corr[r];
        }

        // P = exp(S - m) -> bf16 -> per-wave LDS (A-fragment layout)
        char* pw = Pl[w];
        #pragma unroll
        for (int r = 0; r < 4; ++r) {
            const int q = ((l >> 4) << 2) + r;
            const int qo = q * 128, qm = swz7(q);
            const float mr = mrow[r];
            #pragma unroll
            for (int ni = 0; ni < 4; ++ni) {
                const float p = __expf(sacc[ni][r] - mr);
                const int t = (l & 15) + (ni << 4);
                *(__bf16*)(pw + qo + ((t * 2) ^ qm)) = (__bf16)p;
            }
        }

        // PV (+ ones-column row-sum)
        #pragma unroll
        for (int tg = 0; tg < 2; ++tg) {
            const int q = l & 15;
            bf16x8 pf = *(const bf16x8*)(pw + q * 128 + ((((tg << 2) + (l >> 4)) << 4) ^ swz7(q)));
            #pragma unroll
            for (int nd = 0; nd < 8; ++nd) {
                const int d = (nd << 4) + (l & 15);
                const int m = (d ^ (d >> 3)) & 7;
                bf16x8 vf = *(const bf16x8*)(Vt + d * 128 + ((((tg << 2) + (l >> 4)) ^ m) << 4));
                oacc[nd] = __builtin_amdgcn_mfma_f32_16x16x32_bf16(pf, vf, oacc[nd], 0, 0, 0);
            }
            lacc = __builtin_amdgcn_mfma_f32_16x16x32_bf16(pf, vones, lacc, 0, 0, 0);
        }
    }

    // epilogue: O /= l  (+ qv), bf16 store
    const size_t orow = qrow0 + ((l >> 4) << 2);
    #pragma unroll
    for (int r = 0; r < 4; ++r) {
        const float inv = 1.f / lacc[r];
        #pragma unroll
        for (int nd = 0; nd < 8; ++nd) {
            const size_t c = (l & 15) + (nd << 4);
            float v = oacc[nd][r] * inv;
            if (ADD_QV) v += bf2f(QV[bi + (orow + r) * ld + c]);
            O[bo + (orow + r) * 1024 + c] = f2bf(v);
        }
    }
}

// ---------------------------------------------------------------------------
// LayerNorm over (S,E) per batch on bf16 h1.
// ---------------------------------------------------------------------------
__global__ void ln_partial(const ushort* __restrict__ h1, float2* __restrict__ part)
{
    __shared__ float sa[8];
    const size_t off = ((size_t)blockIdx.x) << 15;
    float s = 0.f, s2 = 0.f;
    for (int i = threadIdx.x; i < 4096; i += 256) {
        uint4 u = *(const uint4*)(h1 + off + (size_t)i * 8);
        const ushort* e = (const ushort*)&u;
        #pragma unroll
        for (int j = 0; j < 8; ++j) { const float v = bf2f(e[j]); s += v; s2 += v * v; }
    }
    #pragma unroll
    for (int m = 1; m < 64; m <<= 1) { s += __shfl_xor(s, m, 64); s2 += __shfl_xor(s2, m, 64); }
    const int w = threadIdx.x >> 6;
    if ((threadIdx.x & 63) == 0) { sa[w * 2] = s; sa[w * 2 + 1] = s2; }
    __syncthreads();
    if (threadIdx.x == 0)
        part[blockIdx.x] = make_float2(sa[0] + sa[2] + sa[4] + sa[6], sa[1] + sa[3] + sa[5] + sa[7]);
}

__global__ void ln_finish(const float2* __restrict__ part, float2* __restrict__ stats)
{
    const int b = threadIdx.x;
    if (b < 8) {
        float s = 0.f, s2 = 0.f;
        for (int c = 0; c < 32; ++c) { const float2 v = part[b * 32 + c]; s += v.x; s2 += v.y; }
        const float mu = s * (1.f / 1048576.f);
        const float var = s2 * (1.f / 1048576.f) - mu * mu;
        stats[b] = make_float2(mu, rsqrtf(var + 1e-5f));
    }
}

__global__ void ln_apply(const ushort* __restrict__ h1, const float2* __restrict__ stats,
                         const float* __restrict__ gw, const float* __restrict__ gb,
                         ushort* __restrict__ hn)
{
    const size_t i = ((size_t)blockIdx.x * 256 + threadIdx.x) * 8;
    const int b = (int)(i >> 20);
    const size_t r = i & 1048575;
    const float2 st = stats[b];
    uint4 uv = *(const uint4*)(h1 + i);
    const float4 w0 = *(const float4*)(gw + r);
    const float4 w1 = *(const float4*)(gw + r + 4);
    const float4 b0 = *(const float4*)(gb + r);
    const float4 b1 = *(const float4*)(gb + r + 4);
    const float wv[8] = {w0.x, w0.y, w0.z, w0.w, w1.x, w1.y, w1.z, w1.w};
    const float bv[8] = {b0.x, b0.y, b0.z, b0.w, b1.x, b1.y, b1.z, b1.w};
    const ushort* ev = (const ushort*)&uv;
    ushort o[8];
    #pragma unroll
    for (int j = 0; j < 8; ++j)
        o[j] = f2bf((bf2f(ev[j]) - st.x) * st.y * wv[j] + bv[j]);
    *(uint4*)(hn + i) = *(const uint4*)o;
}

// ---------------------------------------------------------------------------
extern "C" void kernel_launch(void* const* d_in, const int* in_sizes, int n_in,
                              void* d_out, int out_size, void* d_ws, size_t ws_size,
                              hipStream_t stream)
{
    (void)in_sizes; (void)n_in; (void)out_size; (void)ws_size;
    auto P = [&](int i) { return (const float*)d_in[i]; };

    const size_t MB = 1u << 20;
    char* ws = (char*)d_ws;
    ushort* WB = (ushort*)ws;                       // 32 MB packed bf16 weights
    ushort* B0 = (ushort*)(ws + 32 * MB);           // 6 x 16 MB bf16 buffers
    ushort* B1 = (ushort*)(ws + 48 * MB);
    ushort* B2 = (ushort*)(ws + 64 * MB);
    ushort* B3 = (ushort*)(ws + 80 * MB);
    ushort* B4 = (ushort*)(ws + 96 * MB);
    ushort* B5 = (ushort*)(ws + 112 * MB);
    float*  BP = (float*)(ws + 128 * MB);           // 64 KB packed fp32 biases
    float2* PART = (float2*)(ws + 128 * MB + 65536);
    float2* STATS = PART + 256;

    PtrTab tab;
    const int wsrc[16] = {2,4,6,8,10,14,16,18,20,22,24,26,28,30,32,34};
    for (int i = 0; i < 16; ++i) { tab.w[i] = P(wsrc[i]); tab.b[i] = P(wsrc[i] + 1); }
    tab.x = P(0); tab.y = P(1);

    const dim3 blk(256), gg(512);
    const float SA_SCALE = 0.08838834764831845f;    // 1/sqrt(128)
    auto Wp = [&](int w) { return WB + (size_t)w * 1048576; };
    auto Bp = [&](int w) { return BP + (size_t)w * 1024; };
    const ushort* NUS = nullptr;

    // x_bf16 -> B4, y_bf16 -> B5
    cvt_pack<<<dim3(16392), blk, 0, stream>>>(tab, WB, B4, B5, BP);

    // --- cross attention (all GEMMs N=1024) ---
    gemm_bf16<0,0,0,ushort,ushort><<<gg, blk, 0, stream>>>(B4, Wp(0), Bp(0), NUS, B0, 1024, nullptr, 0);  // q  -> B0
    gemm_bf16<0,0,0,ushort,ushort><<<gg, blk, 0, stream>>>(B4, Wp(1), Bp(1), NUS, B1, 1024, nullptr, 0);  // qv -> B1
    gemm_bf16<0,0,0,ushort,ushort><<<gg, blk, 0, stream>>>(B5, Wp(2), Bp(2), NUS, B2, 1024, nullptr, 0);  // k  -> B2
    gemm_bf16<0,0,1,ushort,ushort><<<gg, blk, 0, stream>>>(B5, Wp(3), Bp(3), NUS, B3, 1024, B3, 0);       // kv^T -> B3
    attn_fwd<1><<<dim3(1024), blk, 0, stream>>>(B0, B2, B3, B1, B4, 1024, 1.0f);                           // -> B4
    gemm_bf16<0,1,0,float,ushort><<<gg, blk, 0, stream>>>(B4, Wp(4), Bp(4), P(0), B5, 1024, nullptr, 0);   // h1 = x + o(ca) -> B5

    // --- LayerNorm over (S,E) per batch: h1=B5 -> hn=B0 ---
    ln_partial<<<dim3(256), blk, 0, stream>>>(B5, PART);
    ln_finish<<<dim3(1), dim3(64), 0, stream>>>(PART, STATS);
    ln_apply<<<dim3(4096), blk, 0, stream>>>(B5, STATS, P(12), P(13), B0);

    // --- FeedForward: hn=B0 -> h2=B3 ---
    gemm_bf16<1,0,0,ushort,ushort><<<gg, blk, 0, stream>>>(B0, Wp(5), Bp(5), NUS, B1, 1024, nullptr, 0);   // f1
    gemm_bf16<1,0,0,ushort,ushort><<<gg, blk, 0, stream>>>(B1, Wp(6), Bp(6), NUS, B2, 1024, nullptr, 0);   // f2
    gemm_bf16<1,1,0,ushort,ushort><<<gg, blk, 0, stream>>>(B2, Wp(7), Bp(7), B0, B3, 1024, nullptr, 0);    // h2 = hn + lr(f3)

    // --- self attention 1 (input h2=B3) ---
    gemm_bf16<0,0,0,ushort,ushort><<<gg, blk, 0, stream>>>(B3, Wp(8),  Bp(8),  NUS, B0, 1024, nullptr, 0); // q1 -> B0
    gemm_bf16<0,0,0,ushort,ushort><<<gg, blk, 0, stream>>>(B3, Wp(9),  Bp(9),  NUS, B1, 1024, nullptr, 0); // k1 -> B1
    gemm_bf16<0,0,1,ushort,ushort><<<gg, blk, 0, stream>>>(B3, Wp(10), Bp(10), NUS, B2, 1024, B2, 0);      // v1^T -> B2
    attn_fwd<0><<<dim3(1024), blk, 0, stream>>>(B0, B1, B2, nullptr, B4, 1024, SA_SCALE);                  // -> B4
    gemm_bf16<0,0,0,ushort,ushort><<<gg, blk, 0, stream>>>(B4, Wp(11), Bp(11), NUS, B5, 1024, nullptr, 0); // h3 -> B5

    // --- self attention 2 (input h3=B5) ---
    gemm_bf16<0,0,0,ushort,ushort><<<gg, blk, 0, stream>>>(B5, Wp(12), Bp(12), NUS, B0, 1024, nullptr, 0); // q2 -> B0
    gemm_bf16<0,0,0,ushort,ushort><<<gg, blk, 0, stream>>>(B5, Wp(13), Bp(13), NUS, B1, 1024, nullptr, 0); // k2 -> B1
    gemm_bf16<0,0,1,ushort,ushort><<<gg, blk, 0, stream>>>(B5, Wp(14), Bp(14), NUS, B2, 1024, B2, 0);      // v2^T -> B2
    attn_fwd<0><<<dim3(1024), blk, 0, stream>>>(B0, B1, B2, nullptr, B4, 1024, SA_SCALE);                  // -> B4
    gemm_bf16<0,0,0,ushort,float><<<gg, blk, 0, stream>>>(B4, Wp(15), Bp(15), NUS, (float*)d_out, 1024, nullptr, 0);
}